// Round 2
// baseline (1097.210 us; speedup 1.0000x reference)
//
#include <hip/hip_runtime.h>
#include <hip/hip_bf16.h>

#define DI __device__ __forceinline__

typedef __attribute__((ext_vector_type(8))) short bf8;
typedef __attribute__((ext_vector_type(4))) float f4;
typedef __attribute__((ext_vector_type(8))) unsigned short us8;

#define LI    2048
#define LT    256
#define SEQ   2304
#define HID   3072
#define NHEAD 24
#define HD    128
#define N1    21504      // 3*HID + MLP
#define QKVW  9216       // 3*HID
#define N2CAT 15360      // HID + MLP

DI unsigned short f2bf(float f) {
  union { float f; unsigned u; } v; v.f = f;
  unsigned r = v.u + 0x7FFFu + ((v.u >> 16) & 1u);
  return (unsigned short)(r >> 16);
}
DI float bf2f(unsigned short h) {
  union { unsigned u; float f; } v; v.u = ((unsigned)h) << 16;
  return v.f;
}

DI void gload16(const void* g, void* l) {
  __builtin_amdgcn_global_load_lds(
      (const __attribute__((address_space(1))) void*)g,
      (__attribute__((address_space(3))) void*)l, 16, 0, 0);
}

DI f4 mfma16(bf8 a, bf8 b, f4 c) {
  return __builtin_amdgcn_mfma_f32_16x16x32_bf16(a, b, c, 0, 0, 0);
}

// ---------------- modulation GEMV: mod = silu(vec) @ mod_w^T + mod_b ----------------
__global__ void k_mod(const float* __restrict__ vec, const float* __restrict__ mw,
                      const float* __restrict__ mb, float* __restrict__ mod) {
  int row = blockIdx.x * 4 + (threadIdx.x >> 6);
  int lane = threadIdx.x & 63;
  const float4* wr = (const float4*)(mw + (size_t)row * HID);
  const float4* vv = (const float4*)vec;
  float s = 0.f;
  for (int i = lane; i < HID / 4; i += 64) {
    float4 w4 = wr[i], x4 = vv[i];
    s += (x4.x / (1.f + __expf(-x4.x))) * w4.x;
    s += (x4.y / (1.f + __expf(-x4.y))) * w4.y;
    s += (x4.z / (1.f + __expf(-x4.z))) * w4.z;
    s += (x4.w / (1.f + __expf(-x4.w))) * w4.w;
  }
#pragma unroll
  for (int m = 32; m; m >>= 1) s += __shfl_xor(s, m);
  if (lane == 0) mod[row] = s + mb[row];
}

// ---------------- layernorm + modulate -> x_mod (bf16) ----------------
__global__ void k_lnmod(const float* __restrict__ img, const float* __restrict__ txt,
                        const float* __restrict__ mod, unsigned short* __restrict__ xmod) {
  int t = blockIdx.x;
  const float* x = (t < LI) ? (img + (size_t)t * HID) : (txt + (size_t)(t - LI) * HID);
  const float4* x4 = (const float4*)x;
  float4 v[3];
  float s = 0.f, ss = 0.f;
#pragma unroll
  for (int j = 0; j < 3; ++j) {
    v[j] = x4[threadIdx.x + j * 256];
    s  += v[j].x + v[j].y + v[j].z + v[j].w;
    ss += v[j].x * v[j].x + v[j].y * v[j].y + v[j].z * v[j].z + v[j].w * v[j].w;
  }
#pragma unroll
  for (int m = 32; m; m >>= 1) { s += __shfl_xor(s, m); ss += __shfl_xor(ss, m); }
  __shared__ float red[8];
  int wv = threadIdx.x >> 6;
  if ((threadIdx.x & 63) == 0) { red[wv] = s; red[4 + wv] = ss; }
  __syncthreads();
  s = red[0] + red[1] + red[2] + red[3];
  ss = red[4] + red[5] + red[6] + red[7];
  float mu = s * (1.f / HID);
  float var = ss * (1.f / HID) - mu * mu;
  float inv = rsqrtf(var + 1e-6f);
  const float* shift = mod;
  const float* scale = mod + HID;
#pragma unroll
  for (int j = 0; j < 3; ++j) {
    int i = threadIdx.x + j * 256;
    int c = i * 4;
    ushort4 o;
    o.x = f2bf((v[j].x - mu) * inv * (1.f + scale[c + 0]) + shift[c + 0]);
    o.y = f2bf((v[j].y - mu) * inv * (1.f + scale[c + 1]) + shift[c + 1]);
    o.z = f2bf((v[j].z - mu) * inv * (1.f + scale[c + 2]) + shift[c + 2]);
    o.w = f2bf((v[j].w - mu) * inv * (1.f + scale[c + 3]) + shift[c + 3]);
    ((ushort4*)xmod)[(size_t)t * (HID / 4) + i] = o;
  }
}

// ---------------- f32 -> bf16 bulk convert ----------------
__global__ void k_f2bf(const float* __restrict__ in, unsigned short* __restrict__ out, int n4) {
  int stride = gridDim.x * blockDim.x;
  for (int i = blockIdx.x * blockDim.x + threadIdx.x; i < n4; i += stride) {
    float4 f = ((const float4*)in)[i];
    ushort4 o;
    o.x = f2bf(f.x); o.y = f2bf(f.y); o.z = f2bf(f.z); o.w = f2bf(f.w);
    ((ushort4*)out)[i] = o;
  }
}

// ---------------- shared GEMM mainloop: C[128x128] = A[128xK] * B[128xK]^T ----------------
// 256 thr = 4 waves (2x2), per wave 64x64 via 4x4 frags of 16x16x32 bf16.
// LDS XOR-swizzled (slot ^= row&7) via pre-swizzled global_load_lds source.
DI void gemm_core(const unsigned short* __restrict__ A, const unsigned short* __restrict__ Bw,
                  int K, int bm, int bn, unsigned short* As, unsigned short* Bs, f4 acc[4][4]) {
  int tid = threadIdx.x;
  int lane = tid & 63;
  int wr = (tid >> 7) & 1;
  int wc = (tid >> 6) & 1;
#pragma unroll
  for (int m = 0; m < 4; ++m)
#pragma unroll
    for (int n = 0; n < 4; ++n) acc[m][n] = (f4){0.f, 0.f, 0.f, 0.f};

  int rbase = tid >> 3;                  // 0..31
  int slg = (tid & 7) ^ (rbase & 7);     // swizzled source 16B slot
  const unsigned short* Ag = A + (size_t)(bm * 128 + rbase) * K + slg * 8;
  const unsigned short* Bg = Bw + (size_t)(bn * 128 + rbase) * K + slg * 8;
  unsigned short* Asd = As + tid * 8;
  unsigned short* Bsd = Bs + tid * 8;

  int rA = wr * 64 + (lane & 15);
  int rB = wc * 64 + (lane & 15);
  int cb = (lane >> 4) * 8;
  int cx = (lane & 7) << 3;

  for (int k0 = 0; k0 < K; k0 += 64) {
    __syncthreads();
#pragma unroll
    for (int j = 0; j < 4; ++j) {
      gload16(Ag + (size_t)(j * 32) * K + k0, Asd + j * 2048);
      gload16(Bg + (size_t)(j * 32) * K + k0, Bsd + j * 2048);
    }
    __syncthreads();
#pragma unroll
    for (int kk = 0; kk < 2; ++kk) {
      bf8 av[4], bv[4];
#pragma unroll
      for (int m = 0; m < 4; ++m)
        av[m] = *(const bf8*)&As[(rA + m * 16) * 64 + ((kk * 32 + cb) ^ cx)];
#pragma unroll
      for (int n = 0; n < 4; ++n)
        bv[n] = *(const bf8*)&Bs[(rB + n * 16) * 64 + ((kk * 32 + cb) ^ cx)];
#pragma unroll
      for (int m = 0; m < 4; ++m)
#pragma unroll
        for (int n = 0; n < 4; ++n)
          acc[m][n] = mfma16(av[m], bv[n], acc[m][n]);
    }
  }
}

// ---------------- GEMM1: x_mod @ w1^T + b1 -> qkv (bf16) / gelu -> attnmlp mlp cols ----------------
__global__ __launch_bounds__(256) void k_gemm1(const unsigned short* __restrict__ xmod,
    const unsigned short* __restrict__ w1b, const float* __restrict__ b1,
    unsigned short* __restrict__ qkv, unsigned short* __restrict__ amlp) {
  __shared__ unsigned short As[128 * 64], Bs[128 * 64];
  int nb = gridDim.x;
  int b = blockIdx.x;
  int bsw = (b & 7) * (nb >> 3) + (b >> 3);   // XCD swizzle (nb%8==0)
  int bm = bsw % 18, bn = bsw / 18;           // bm-fastest
  f4 acc[4][4];
  gemm_core(xmod, w1b, HID, bm, bn, As, Bs, acc);
  int lane = threadIdx.x & 63;
  int wr = (threadIdx.x >> 7) & 1, wc = (threadIdx.x >> 6) & 1;
  int r0 = bm * 128 + wr * 64 + ((lane >> 4) << 2);
  int c0 = bn * 128 + wc * 64 + (lane & 15);
  bool isqkv = (bn * 128) < QKVW;
#pragma unroll
  for (int m = 0; m < 4; ++m) {
#pragma unroll
    for (int n = 0; n < 4; ++n) {
      int col = c0 + n * 16;
      float bias = b1[col];
#pragma unroll
      for (int j = 0; j < 4; ++j) {
        int row = r0 + m * 16 + j;
        float v = acc[m][n][j] + bias;
        if (isqkv) {
          qkv[(size_t)row * QKVW + col] = f2bf(v);
        } else {
          float u = 0.7978845608f * (v + 0.044715f * v * v * v);
          float g = v / (1.f + __expf(-2.f * u));   // v*sigmoid(2u) == gelu-tanh, overflow-safe
          amlp[(size_t)row * N2CAT + (HID + col - QKVW)] = f2bf(g);
        }
      }
    }
  }
}

// ---------------- GEMM2: [attn|mlp] @ w2^T + b2, gated residual -> f32 out ----------------
__global__ __launch_bounds__(256) void k_gemm2(const unsigned short* __restrict__ amlp,
    const unsigned short* __restrict__ w2b, const float* __restrict__ b2,
    const float* __restrict__ img, const float* __restrict__ txt,
    const float* __restrict__ gate, float* __restrict__ out) {
  __shared__ unsigned short As[128 * 64], Bs[128 * 64];
  int nb = gridDim.x;
  int b = blockIdx.x;
  int bsw = (b & 7) * (nb >> 3) + (b >> 3);
  int bm = bsw % 18, bn = bsw / 18;
  f4 acc[4][4];
  gemm_core(amlp, w2b, N2CAT, bm, bn, As, Bs, acc);
  int lane = threadIdx.x & 63;
  int wr = (threadIdx.x >> 7) & 1, wc = (threadIdx.x >> 6) & 1;
  int r0 = bm * 128 + wr * 64 + ((lane >> 4) << 2);
  int c0 = bn * 128 + wc * 64 + (lane & 15);
#pragma unroll
  for (int m = 0; m < 4; ++m) {
#pragma unroll
    for (int n = 0; n < 4; ++n) {
      int col = c0 + n * 16;
      float bias = b2[col];
      float gt = gate[col];
#pragma unroll
      for (int j = 0; j < 4; ++j) {
        int row = r0 + m * 16 + j;
        float v = acc[m][n][j] + bias;
        float res = (row < LI) ? img[(size_t)row * HID + col]
                               : txt[(size_t)(row - LI) * HID + col];
        out[(size_t)row * HID + col] = res + gt * v;
      }
    }
  }
}

// ---------------- per-(token,head) RMSNorm + RoPE on q,k (in place, bf16) ----------------
__global__ void k_qknorm(unsigned short* __restrict__ qkv, const float* __restrict__ qw,
                         const float* __restrict__ kw, const float* __restrict__ fcos,
                         const float* __restrict__ fsin) {
  int gw = (blockIdx.x * 256 + threadIdx.x) >> 6;
  int lane = threadIdx.x & 63;
  int token = gw / NHEAD, head = gw - token * NHEAD;
  bool dorope = token < LI;
  float c = 1.f, sn = 0.f;
  if (dorope) { c = fcos[token * HD + 2 * lane]; sn = fsin[token * HD + 2 * lane]; }
#pragma unroll
  for (int qk = 0; qk < 2; ++qk) {
    unsigned short* p = qkv + (size_t)token * QKVW + qk * HID + head * HD;
    unsigned u = ((const unsigned*)p)[lane];
    float x0 = bf2f((unsigned short)(u & 0xffff));
    float x1 = bf2f((unsigned short)(u >> 16));
    float ss = x0 * x0 + x1 * x1;
#pragma unroll
    for (int m2 = 32; m2; m2 >>= 1) ss += __shfl_xor(ss, m2);
    float inv = rsqrtf(ss * (1.f / HD) + 1e-6f);
    const float* w = qk ? kw : qw;
    float y0 = x0 * inv * w[2 * lane];
    float y1 = x1 * inv * w[2 * lane + 1];
    if (dorope) { float r0 = y0 * c - y1 * sn; float r1 = y1 * c + y0 * sn; y0 = r0; y1 = r1; }
    ((unsigned*)p)[lane] = ((unsigned)f2bf(y0)) | (((unsigned)f2bf(y1)) << 16);
  }
}

// ---------------- transpose V: qkv v-slice [S][24*128] -> vt [24][128][S] ----------------
__global__ void k_vt(const unsigned short* __restrict__ qkv, unsigned short* __restrict__ vt) {
  int b = blockIdx.x;                 // 24*36*2
  int h = b / 72; int rem = b - h * 72; int tt = rem >> 1; int dd = rem & 1;
  int t0 = tt * 64, d0 = dd * 64;
  __shared__ unsigned short tile[64 * 65];
  int tid = threadIdx.x;
#pragma unroll
  for (int j = 0; j < 2; ++j) {
    int idx = j * 256 + tid;
    int row = idx >> 3, s = idx & 7;   // 64 rows x 8 slots of 8 halfwords
    us8 vv = *(const us8*)(qkv + (size_t)(t0 + row) * QKVW + 2 * HID + h * HD + d0 + s * 8);
#pragma unroll
    for (int i = 0; i < 8; ++i) tile[row * 65 + s * 8 + i] = vv[i];
  }
  __syncthreads();
#pragma unroll
  for (int j = 0; j < 2; ++j) {
    int idx = j * 256 + tid;
    int dr = idx >> 3, sl = idx & 7;
    us8 o;
#pragma unroll
    for (int i = 0; i < 8; ++i) o[i] = tile[(sl * 8 + i) * 65 + dr];
    *(us8*)(vt + (size_t)(h * HD + d0 + dr) * SEQ + t0 + sl * 8) = o;
  }
}

// ---------------- flash attention: 64-row Q tile per block, 4 waves, online softmax ----------------
__global__ __launch_bounds__(256) void k_attn(const unsigned short* __restrict__ qkv,
                                              const unsigned short* __restrict__ vt,
                                              unsigned short* __restrict__ amlp) {
  int b = blockIdx.x;                           // 864 = 24 heads * 36 qtiles
  int bsw = (b & 7) * 108 + (b >> 3);
  int head = bsw / 36, qt = bsw - head * 36;
  int tid = threadIdx.x, lane = tid & 63, wv = tid >> 6;
  __shared__ unsigned short Qs[64 * 128], Ks[64 * 128], Vs[128 * 64], Ps[64 * 64];
  int qbase = qt * 64;

  { // stage Q once (swizzled source, linear LDS)
    int row = tid >> 4, sl = tid & 15;
    int slg = sl ^ (row & 7);
    const unsigned short* qg = qkv + (size_t)(qbase + row) * QKVW + head * HD + slg * 8;
#pragma unroll
    for (int j = 0; j < 4; ++j)
      gload16(qg + (size_t)(j * 16) * QKVW, &Qs[(j * 256 + tid) * 8]);
  }

  float mrun[4], lrun[4];
  f4 oacc[8];
#pragma unroll
  for (int j = 0; j < 4; ++j) { mrun[j] = -1e30f; lrun[j] = 0.f; }
#pragma unroll
  for (int n = 0; n < 8; ++n) oacc[n] = (f4){0.f, 0.f, 0.f, 0.f};
  bf8 qf[4];

  for (int kt = 0; kt < SEQ / 64; ++kt) {
    __syncthreads();
    { // stage K tile [64][128]
      int rloc = tid >> 4, sl = tid & 15, slg = sl ^ (rloc & 7);
      const unsigned short* kg =
          qkv + HID + (size_t)(kt * 64 + rloc) * QKVW + head * HD + slg * 8;
#pragma unroll
      for (int j = 0; j < 4; ++j) gload16(kg + (size_t)(j * 16) * QKVW, &Ks[(j * 256 + tid) * 8]);
    }
    { // stage V^T tile [128][64]
      int rloc = tid >> 3, sl = tid & 7, slg = sl ^ (rloc & 7);
      const unsigned short* vg = vt + (size_t)(head * HD + rloc) * SEQ + kt * 64 + slg * 8;
#pragma unroll
      for (int j = 0; j < 4; ++j) gload16(vg + (size_t)(j * 32) * SEQ, &Vs[(j * 256 + tid) * 8]);
    }
    __syncthreads();
    if (kt == 0) {
#pragma unroll
      for (int kk = 0; kk < 4; ++kk) {
        int row = wv * 16 + (lane & 15);
        int col = (kk * 32 + ((lane >> 4) * 8)) ^ ((lane & 7) << 3);
        qf[kk] = *(const bf8*)&Qs[row * 128 + col];
      }
    }
    // QK^T -> sacc[n] : S[16q][64k] per wave
    f4 sacc[4];
#pragma unroll
    for (int n = 0; n < 4; ++n) sacc[n] = (f4){0.f, 0.f, 0.f, 0.f};
#pragma unroll
    for (int kk = 0; kk < 4; ++kk) {
#pragma unroll
      for (int n = 0; n < 4; ++n) {
        int row = n * 16 + (lane & 15);
        int col = (kk * 32 + ((lane >> 4) * 8)) ^ ((lane & 7) << 3);
        bf8 kf = *(const bf8*)&Ks[row * 128 + col];
        sacc[n] = mfma16(qf[kk], kf, sacc[n]);
      }
    }
    const float SC = 0.08838834764831845f;
    float mj[4];
#pragma unroll
    for (int j = 0; j < 4; ++j)
      mj[j] = fmaxf(fmaxf(sacc[0][j], sacc[1][j]), fmaxf(sacc[2][j], sacc[3][j]));
#pragma unroll
    for (int j = 0; j < 4; ++j) {
#pragma unroll
      for (int mk = 8; mk; mk >>= 1) mj[j] = fmaxf(mj[j], __shfl_xor(mj[j], mk));
    }
    float resc[4], psum[4];
#pragma unroll
    for (int j = 0; j < 4; ++j) {
      float nm = fmaxf(mrun[j], mj[j] * SC);
      resc[j] = __expf(mrun[j] - nm);
      mrun[j] = nm;
      psum[j] = 0.f;
    }
#pragma unroll
    for (int n = 0; n < 4; ++n) {
#pragma unroll
      for (int j = 0; j < 4; ++j) {
        float p = __expf(sacc[n][j] * SC - mrun[j]);
        psum[j] += p;
        int row = wv * 16 + ((lane >> 4) << 2) + j;
        int col = (n * 16 + (lane & 15)) ^ ((row & 7) << 3);
        Ps[row * 64 + col] = f2bf(p);
      }
    }
#pragma unroll
    for (int j = 0; j < 4; ++j) {
#pragma unroll
      for (int mk = 8; mk; mk >>= 1) psum[j] += __shfl_xor(psum[j], mk);
      lrun[j] = lrun[j] * resc[j] + psum[j];
    }
#pragma unroll
    for (int n = 0; n < 8; ++n) {
#pragma unroll
      for (int j = 0; j < 4; ++j) oacc[n][j] *= resc[j];
    }
    // PV
#pragma unroll
    for (int kk = 0; kk < 2; ++kk) {
      int prow = wv * 16 + (lane & 15);
      int pcol = (kk * 32 + ((lane >> 4) * 8)) ^ ((lane & 7) << 3);
      bf8 pa = *(const bf8*)&Ps[prow * 64 + pcol];
#pragma unroll
      for (int n = 0; n < 8; ++n) {
        int vrow = n * 16 + (lane & 15);
        int vcol = (kk * 32 + ((lane >> 4) * 8)) ^ ((vrow & 7) << 3);
        bf8 vf = *(const bf8*)&Vs[vrow * 64 + vcol];
        oacc[n] = mfma16(pa, vf, oacc[n]);
      }
    }
  }
  // epilogue: O /= l, write bf16 into attnmlp cols [0,3072)
#pragma unroll
  for (int j = 0; j < 4; ++j) {
    float invl = 1.f / lrun[j];
    int row = qbase + wv * 16 + ((lane >> 4) << 2) + j;
#pragma unroll
    for (int n = 0; n < 8; ++n) {
      int col = head * HD + n * 16 + (lane & 15);
      amlp[(size_t)row * N2CAT + col] = f2bf(oacc[n][j] * invl);
    }
  }
}

extern "C" void kernel_launch(void* const* d_in, const int* in_sizes, int n_in,
                              void* d_out, int out_size, void* d_ws, size_t ws_size,
                              hipStream_t stream) {
  (void)in_sizes; (void)n_in; (void)out_size; (void)ws_size;
  const float* img  = (const float*)d_in[0];
  const float* txt  = (const float*)d_in[1];
  const float* vec  = (const float*)d_in[2];
  const float* fcos = (const float*)d_in[3];
  const float* fsin = (const float*)d_in[4];
  const float* w1   = (const float*)d_in[5];
  const float* b1   = (const float*)d_in[6];
  const float* w2   = (const float*)d_in[7];
  const float* b2   = (const float*)d_in[8];
  const float* qnw  = (const float*)d_in[9];
  const float* knw  = (const float*)d_in[10];
  const float* mw   = (const float*)d_in[11];
  const float* mb   = (const float*)d_in[12];
  float* out = (float*)d_out;

  char* ws = (char*)d_ws;
  float*          mod  = (float*)(ws);                          // 36,864 B
  unsigned short* xmod = (unsigned short*)(ws + 40960);         // 14,155,776 B
  unsigned short* w1b  = (unsigned short*)(ws + 14196736);      // 132,120,576 B
  unsigned short* qkv  = (unsigned short*)(ws + 146317312);     // 42,467,328 B
  unsigned short* amlp = (unsigned short*)(ws + 188784640);     // 70,778,880 B (end ~259.6MB)
  unsigned short* vtb  = xmod;   // x_mod dead after GEMM1
  unsigned short* w2b  = w1b;    // w1 bf16 dead after GEMM1

  k_mod<<<QKVW / 4, 256, 0, stream>>>(vec, mw, mb, mod);
  k_lnmod<<<SEQ, 256, 0, stream>>>(img, txt, mod, xmod);
  k_f2bf<<<2048, 256, 0, stream>>>(w1, w1b, N1 * HID / 4);
  k_gemm1<<<18 * 168, 256, 0, stream>>>(xmod, w1b, b1, qkv, amlp);
  k_qknorm<<<SEQ * NHEAD / 4, 256, 0, stream>>>(qkv, qnw, knw, fcos, fsin);
  k_vt<<<NHEAD * 36 * 2, 256, 0, stream>>>(qkv, vtb);
  k_f2bf<<<2048, 256, 0, stream>>>(w2, w2b, HID * N2CAT / 4);
  k_attn<<<864, 256, 0, stream>>>(qkv, vtb, amlp);
  k_gemm2<<<18 * 24, 256, 0, stream>>>(amlp, w2b, b2, img, txt, mod + 2 * HID, out);
}

// Round 3
// 1031.163 us; speedup vs baseline: 1.0641x; 1.0641x over previous
//
#include <hip/hip_runtime.h>
#include <hip/hip_bf16.h>

#define DI __device__ __forceinline__

typedef __attribute__((ext_vector_type(8))) short bf8;
typedef __attribute__((ext_vector_type(4))) float f4;
typedef __attribute__((ext_vector_type(8))) unsigned short us8;

#define LI    2048
#define LT    256
#define SEQ   2304
#define HID   3072
#define NHEAD 24
#define HD    128
#define N1    21504      // 3*HID + MLP
#define QKVW  9216       // 3*HID
#define N2CAT 15360      // HID + MLP

DI unsigned short f2bf(float f) {
  union { float f; unsigned u; } v; v.f = f;
  unsigned r = v.u + 0x7FFFu + ((v.u >> 16) & 1u);
  return (unsigned short)(r >> 16);
}
DI float bf2f(unsigned short h) {
  union { unsigned u; float f; } v; v.u = ((unsigned)h) << 16;
  return v.f;
}

DI void gload16(const void* g, void* l) {
  __builtin_amdgcn_global_load_lds(
      (const __attribute__((address_space(1))) void*)g,
      (__attribute__((address_space(3))) void*)l, 16, 0, 0);
}

DI f4 mfma16(bf8 a, bf8 b, f4 c) {
  return __builtin_amdgcn_mfma_f32_16x16x32_bf16(a, b, c, 0, 0, 0);
}

// ---------------- modulation GEMV: mod = silu(vec) @ mod_w^T + mod_b ----------------
__global__ void k_mod(const float* __restrict__ vec, const float* __restrict__ mw,
                      const float* __restrict__ mb, float* __restrict__ mod) {
  int row = blockIdx.x * 4 + (threadIdx.x >> 6);
  int lane = threadIdx.x & 63;
  const float4* wr = (const float4*)(mw + (size_t)row * HID);
  const float4* vv = (const float4*)vec;
  float s = 0.f;
  for (int i = lane; i < HID / 4; i += 64) {
    float4 w4 = wr[i], x4 = vv[i];
    s += (x4.x / (1.f + __expf(-x4.x))) * w4.x;
    s += (x4.y / (1.f + __expf(-x4.y))) * w4.y;
    s += (x4.z / (1.f + __expf(-x4.z))) * w4.z;
    s += (x4.w / (1.f + __expf(-x4.w))) * w4.w;
  }
#pragma unroll
  for (int m = 32; m; m >>= 1) s += __shfl_xor(s, m);
  if (lane == 0) mod[row] = s + mb[row];
}

// ---------------- layernorm + modulate -> x_mod (bf16) ----------------
__global__ void k_lnmod(const float* __restrict__ img, const float* __restrict__ txt,
                        const float* __restrict__ mod, unsigned short* __restrict__ xmod) {
  int t = blockIdx.x;
  const float* x = (t < LI) ? (img + (size_t)t * HID) : (txt + (size_t)(t - LI) * HID);
  const float4* x4 = (const float4*)x;
  float4 v[3];
  float s = 0.f, ss = 0.f;
#pragma unroll
  for (int j = 0; j < 3; ++j) {
    v[j] = x4[threadIdx.x + j * 256];
    s  += v[j].x + v[j].y + v[j].z + v[j].w;
    ss += v[j].x * v[j].x + v[j].y * v[j].y + v[j].z * v[j].z + v[j].w * v[j].w;
  }
#pragma unroll
  for (int m = 32; m; m >>= 1) { s += __shfl_xor(s, m); ss += __shfl_xor(ss, m); }
  __shared__ float red[8];
  int wv = threadIdx.x >> 6;
  if ((threadIdx.x & 63) == 0) { red[wv] = s; red[4 + wv] = ss; }
  __syncthreads();
  s = red[0] + red[1] + red[2] + red[3];
  ss = red[4] + red[5] + red[6] + red[7];
  float mu = s * (1.f / HID);
  float var = ss * (1.f / HID) - mu * mu;
  float inv = rsqrtf(var + 1e-6f);
  const float* shift = mod;
  const float* scale = mod + HID;
#pragma unroll
  for (int j = 0; j < 3; ++j) {
    int i = threadIdx.x + j * 256;
    int c = i * 4;
    ushort4 o;
    o.x = f2bf((v[j].x - mu) * inv * (1.f + scale[c + 0]) + shift[c + 0]);
    o.y = f2bf((v[j].y - mu) * inv * (1.f + scale[c + 1]) + shift[c + 1]);
    o.z = f2bf((v[j].z - mu) * inv * (1.f + scale[c + 2]) + shift[c + 2]);
    o.w = f2bf((v[j].w - mu) * inv * (1.f + scale[c + 3]) + shift[c + 3]);
    ((ushort4*)xmod)[(size_t)t * (HID / 4) + i] = o;
  }
}

// ---------------- f32 -> bf16 bulk convert ----------------
__global__ void k_f2bf(const float* __restrict__ in, unsigned short* __restrict__ out, int n4) {
  int stride = gridDim.x * blockDim.x;
  for (int i = blockIdx.x * blockDim.x + threadIdx.x; i < n4; i += stride) {
    float4 f = ((const float4*)in)[i];
    ushort4 o;
    o.x = f2bf(f.x); o.y = f2bf(f.y); o.z = f2bf(f.z); o.w = f2bf(f.w);
    ((ushort4*)out)[i] = o;
  }
}

// ================= GEMM1: 256x256 tile, BK=64, 8-wave, 8-phase pipelined =================
// x_mod[2304][3072] @ w1b[21504][3072]^T. Grid 9*84=756, 512 thr, 128 KiB LDS.
// Phases: ph1 reads ALL frags of buf0 (24 ds_read_b128) -> buf0 free; ph2-5 stage
// next-even K-tile into buf0; ph5 reads all of buf1; ph6-8 + next ph1 stage next-odd
// tile into buf1. vmcnt(6) + s_barrier at ph4/ph8 ends completes exactly the K-tile
// needed next. Raw s_barrier (no compiler vmcnt(0) drain).
#define BAR()    asm volatile("s_barrier" ::: "memory")
#define VMCNT6() asm volatile("s_waitcnt vmcnt(6)" ::: "memory")
#define LGKM0()  do { asm volatile("s_waitcnt lgkmcnt(0)" ::: "memory"); \
                      __builtin_amdgcn_sched_barrier(0); } while (0)

__global__ __launch_bounds__(512, 2) void k_gemm1(const unsigned short* __restrict__ xmod,
    const unsigned short* __restrict__ w1b, const float* __restrict__ b1,
    unsigned short* __restrict__ qkv, unsigned short* __restrict__ amlp) {
  __shared__ unsigned short As[2][256 * 64];
  __shared__ unsigned short Bs[2][256 * 64];
  const int K = HID;          // 3072
  const int NT = K / 64;      // 48 K-tiles, 24 iterations
  int tid = threadIdx.x, lane = tid & 63, wid = tid >> 6;
  int wr = wid >> 2, wc = wid & 3;

  // bijective XCD swizzle (nwg=756: q=94, r=4)
  int b = blockIdx.x;
  const int Q = 756 / 8, R = 756 % 8;
  int xcd = b & 7, idx = b >> 3;
  int wg = (xcd < R ? xcd * (Q + 1) : R * (Q + 1) + (xcd - R) * Q) + idx;
  int bm = wg % 9, bn = wg / 9;

  const unsigned short* Ag = xmod + (size_t)bm * 256 * K;
  const unsigned short* Bg = w1b + (size_t)bn * 256 * K;

  // staging thread-constants: lane covers row +(lane>>3), stored granule lane&7,
  // source granule pre-swizzled so LDS[row][gs] = G[row][gs ^ (row&7)]
  int sgran = (lane & 7) ^ ((lane >> 3) & 7);
  int srow = wid * 16 + (lane >> 3);

#define STAGE_A(bufi, t, hh) do { \
    gload16(Ag + (size_t)((hh)*128 + srow) * K + (t)*64 + sgran*8, \
            &As[bufi][((hh)*128 + wid*16) * 64]); \
    gload16(Ag + (size_t)((hh)*128 + 8 + srow) * K + (t)*64 + sgran*8, \
            &As[bufi][((hh)*128 + wid*16 + 8) * 64]); \
  } while (0)
#define STAGE_B(bufi, t, hh) do { \
    gload16(Bg + (size_t)((hh)*128 + srow) * K + (t)*64 + sgran*8, \
            &Bs[bufi][((hh)*128 + wid*16) * 64]); \
    gload16(Bg + (size_t)((hh)*128 + 8 + srow) * K + (t)*64 + sgran*8, \
            &Bs[bufi][((hh)*128 + wid*16 + 8) * 64]); \
  } while (0)

  // fragment read constants
  int rA = wr * 128 + (lane & 15);
  int rB = wc * 64 + (lane & 15);
  int qq = lane >> 4, l7 = lane & 7;

  f4 acc[8][4];
#pragma unroll
  for (int m = 0; m < 8; ++m)
#pragma unroll
    for (int n = 0; n < 4; ++n) acc[m][n] = (f4){0.f, 0.f, 0.f, 0.f};
  bf8 a[8][2], bfr[4][2];

#define LOADFRAGS(bufi) do { \
    _Pragma("unroll") for (int m = 0; m < 8; ++m) \
      _Pragma("unroll") for (int s = 0; s < 2; ++s) \
        a[m][s] = *(const bf8*)&As[bufi][(rA + m*16)*64 + (((s*4 + qq) ^ l7) << 3)]; \
    _Pragma("unroll") for (int n = 0; n < 4; ++n) \
      _Pragma("unroll") for (int s = 0; s < 2; ++s) \
        bfr[n][s] = *(const bf8*)&Bs[bufi][(rB + n*16)*64 + (((s*4 + qq) ^ l7) << 3)]; \
  } while (0)

#define QUAD(mh, nh) do { \
    __builtin_amdgcn_s_setprio(1); \
    _Pragma("unroll") for (int m = 4*(mh); m < 4*(mh)+4; ++m) \
      _Pragma("unroll") for (int n = 2*(nh); n < 2*(nh)+2; ++n) \
        _Pragma("unroll") for (int s = 0; s < 2; ++s) \
          acc[m][n] = mfma16(a[m][s], bfr[n][s], acc[m][n]); \
    __builtin_amdgcn_s_setprio(0); \
  } while (0)

  // prologue: tile0 -> buf0 (4 halves), tile1 -> buf1 (3 halves; h3 staged at ph1)
  STAGE_A(0, 0, 0); STAGE_A(0, 0, 1); STAGE_B(0, 0, 0); STAGE_B(0, 0, 1);
  STAGE_A(1, 1, 0); STAGE_A(1, 1, 1); STAGE_B(1, 1, 0);
  VMCNT6();   // completes tile0's 8 loads
  BAR();

  for (int i = 0; i < NT / 2; ++i) {
    int t1 = 2 * i + 1;
    int t2 = 2 * i + 2; if (t2 > NT - 1) t2 = NT - 1;
    int t3 = 2 * i + 3; if (t3 > NT - 1) t3 = NT - 1;
    // ph1: read all of buf0; finish staging buf1's tile (B half1)
    LOADFRAGS(0);
    STAGE_B(1, t1, 1);
    LGKM0();
    QUAD(0, 0);
    BAR();               // buf0 fully read -> may be overwritten
    // ph2-4: stage next-even tile into buf0
    STAGE_A(0, t2, 0); QUAD(0, 1);
    STAGE_A(0, t2, 1); QUAD(1, 0);
    STAGE_B(0, t2, 0); QUAD(1, 1);
    VMCNT6();            // completes buf1's tile (t1)
    BAR();
    // ph5: read all of buf1; last half of next-even tile
    LOADFRAGS(1);
    STAGE_B(0, t2, 1);
    LGKM0();
    QUAD(0, 0);
    BAR();               // buf1 fully read -> may be overwritten
    // ph6-8: stage next-odd tile into buf1
    STAGE_A(1, t3, 0); QUAD(0, 1);
    STAGE_A(1, t3, 1); QUAD(1, 0);
    STAGE_B(1, t3, 0); QUAD(1, 1);
    VMCNT6();            // completes buf0's next tile (t2)
    BAR();
  }

  // epilogue: bias + qkv/gelu split
  int r0 = bm * 256 + wr * 128 + ((lane >> 4) << 2);
  int c0 = bn * 256 + wc * 64 + (lane & 15);
  bool isqkv = (bn * 256) < QKVW;
#pragma unroll
  for (int m = 0; m < 8; ++m) {
#pragma unroll
    for (int n = 0; n < 4; ++n) {
      int col = c0 + n * 16;
      float bias = b1[col];
#pragma unroll
      for (int j = 0; j < 4; ++j) {
        int row = r0 + m * 16 + j;
        float v = acc[m][n][j] + bias;
        if (isqkv) {
          qkv[(size_t)row * QKVW + col] = f2bf(v);
        } else {
          float u = 0.7978845608f * (v + 0.044715f * v * v * v);
          float g = v / (1.f + __expf(-2.f * u));
          amlp[(size_t)row * N2CAT + (col - 6144)] = f2bf(g);
        }
      }
    }
  }
#undef STAGE_A
#undef STAGE_B
#undef LOADFRAGS
#undef QUAD
}

// ---------------- shared 128x128 GEMM mainloop (used by gemm2) ----------------
DI void gemm_core(const unsigned short* __restrict__ A, const unsigned short* __restrict__ Bw,
                  int K, int bm, int bn, unsigned short* As, unsigned short* Bs, f4 acc[4][4]) {
  int tid = threadIdx.x;
  int lane = tid & 63;
  int wr = (tid >> 7) & 1;
  int wc = (tid >> 6) & 1;
#pragma unroll
  for (int m = 0; m < 4; ++m)
#pragma unroll
    for (int n = 0; n < 4; ++n) acc[m][n] = (f4){0.f, 0.f, 0.f, 0.f};

  int rbase = tid >> 3;
  int slg = (tid & 7) ^ (rbase & 7);
  const unsigned short* Ag = A + (size_t)(bm * 128 + rbase) * K + slg * 8;
  const unsigned short* Bg = Bw + (size_t)(bn * 128 + rbase) * K + slg * 8;
  unsigned short* Asd = As + tid * 8;
  unsigned short* Bsd = Bs + tid * 8;

  int rA = wr * 64 + (lane & 15);
  int rB = wc * 64 + (lane & 15);
  int cb = (lane >> 4) * 8;
  int cx = (lane & 7) << 3;

  for (int k0 = 0; k0 < K; k0 += 64) {
    __syncthreads();
#pragma unroll
    for (int j = 0; j < 4; ++j) {
      gload16(Ag + (size_t)(j * 32) * K + k0, Asd + j * 2048);
      gload16(Bg + (size_t)(j * 32) * K + k0, Bsd + j * 2048);
    }
    __syncthreads();
#pragma unroll
    for (int kk = 0; kk < 2; ++kk) {
      bf8 av[4], bv[4];
#pragma unroll
      for (int m = 0; m < 4; ++m)
        av[m] = *(const bf8*)&As[(rA + m * 16) * 64 + ((kk * 32 + cb) ^ cx)];
#pragma unroll
      for (int n = 0; n < 4; ++n)
        bv[n] = *(const bf8*)&Bs[(rB + n * 16) * 64 + ((kk * 32 + cb) ^ cx)];
#pragma unroll
      for (int m = 0; m < 4; ++m)
#pragma unroll
        for (int n = 0; n < 4; ++n)
          acc[m][n] = mfma16(av[m], bv[n], acc[m][n]);
    }
  }
}

// ---------------- GEMM2: [attn|mlp] @ w2^T + b2, gated residual -> f32 out ----------------
__global__ __launch_bounds__(256) void k_gemm2(const unsigned short* __restrict__ amlp,
    const unsigned short* __restrict__ w2b, const float* __restrict__ b2,
    const float* __restrict__ img, const float* __restrict__ txt,
    const float* __restrict__ gate, float* __restrict__ out) {
  __shared__ unsigned short As[128 * 64], Bs[128 * 64];
  int nb = gridDim.x;
  int b = blockIdx.x;
  int bsw = (b & 7) * (nb >> 3) + (b >> 3);
  int bm = bsw % 18, bn = bsw / 18;
  f4 acc[4][4];
  gemm_core(amlp, w2b, N2CAT, bm, bn, As, Bs, acc);
  int lane = threadIdx.x & 63;
  int wr = (threadIdx.x >> 7) & 1, wc = (threadIdx.x >> 6) & 1;
  int r0 = bm * 128 + wr * 64 + ((lane >> 4) << 2);
  int c0 = bn * 128 + wc * 64 + (lane & 15);
#pragma unroll
  for (int m = 0; m < 4; ++m) {
#pragma unroll
    for (int n = 0; n < 4; ++n) {
      int col = c0 + n * 16;
      float bias = b2[col];
      float gt = gate[col];
#pragma unroll
      for (int j = 0; j < 4; ++j) {
        int row = r0 + m * 16 + j;
        float v = acc[m][n][j] + bias;
        float res = (row < LI) ? img[(size_t)row * HID + col]
                               : txt[(size_t)(row - LI) * HID + col];
        out[(size_t)row * HID + col] = res + gt * v;
      }
    }
  }
}

// ---------------- per-(token,head) RMSNorm + RoPE on q,k (in place, bf16) ----------------
__global__ void k_qknorm(unsigned short* __restrict__ qkv, const float* __restrict__ qw,
                         const float* __restrict__ kw, const float* __restrict__ fcos,
                         const float* __restrict__ fsin) {
  int gw = (blockIdx.x * 256 + threadIdx.x) >> 6;
  int lane = threadIdx.x & 63;
  int token = gw / NHEAD, head = gw - token * NHEAD;
  bool dorope = token < LI;
  float c = 1.f, sn = 0.f;
  if (dorope) { c = fcos[token * HD + 2 * lane]; sn = fsin[token * HD + 2 * lane]; }
#pragma unroll
  for (int qk = 0; qk < 2; ++qk) {
    unsigned short* p = qkv + (size_t)token * QKVW + qk * HID + head * HD;
    unsigned u = ((const unsigned*)p)[lane];
    float x0 = bf2f((unsigned short)(u & 0xffff));
    float x1 = bf2f((unsigned short)(u >> 16));
    float ss = x0 * x0 + x1 * x1;
#pragma unroll
    for (int m2 = 32; m2; m2 >>= 1) ss += __shfl_xor(ss, m2);
    float inv = rsqrtf(ss * (1.f / HD) + 1e-6f);
    const float* w = qk ? kw : qw;
    float y0 = x0 * inv * w[2 * lane];
    float y1 = x1 * inv * w[2 * lane + 1];
    if (dorope) { float r0 = y0 * c - y1 * sn; float r1 = y1 * c + y0 * sn; y0 = r0; y1 = r1; }
    ((unsigned*)p)[lane] = ((unsigned)f2bf(y0)) | (((unsigned)f2bf(y1)) << 16);
  }
}

// ---------------- transpose V: qkv v-slice [S][24*128] -> vt [24][128][S] ----------------
__global__ void k_vt(const unsigned short* __restrict__ qkv, unsigned short* __restrict__ vt) {
  int b = blockIdx.x;                 // 24*36*2
  int h = b / 72; int rem = b - h * 72; int tt = rem >> 1; int dd = rem & 1;
  int t0 = tt * 64, d0 = dd * 64;
  __shared__ unsigned short tile[64 * 65];
  int tid = threadIdx.x;
#pragma unroll
  for (int j = 0; j < 2; ++j) {
    int idx = j * 256 + tid;
    int row = idx >> 3, s = idx & 7;
    us8 vv = *(const us8*)(qkv + (size_t)(t0 + row) * QKVW + 2 * HID + h * HD + d0 + s * 8);
#pragma unroll
    for (int i = 0; i < 8; ++i) tile[row * 65 + s * 8 + i] = vv[i];
  }
  __syncthreads();
#pragma unroll
  for (int j = 0; j < 2; ++j) {
    int idx = j * 256 + tid;
    int dr = idx >> 3, sl = idx & 7;
    us8 o;
#pragma unroll
    for (int i = 0; i < 8; ++i) o[i] = tile[(sl * 8 + i) * 65 + dr];
    *(us8*)(vt + (size_t)(h * HD + d0 + dr) * SEQ + t0 + sl * 8) = o;
  }
}

// ---------------- flash attention: 64-row Q tile per block, 4 waves, online softmax ----------------
__global__ __launch_bounds__(256) void k_attn(const unsigned short* __restrict__ qkv,
                                              const unsigned short* __restrict__ vt,
                                              unsigned short* __restrict__ amlp) {
  int b = blockIdx.x;                           // 864 = 24 heads * 36 qtiles
  int bsw = (b & 7) * 108 + (b >> 3);
  int head = bsw / 36, qt = bsw - head * 36;
  int tid = threadIdx.x, lane = tid & 63, wv = tid >> 6;
  __shared__ unsigned short Qs[64 * 128], Ks[64 * 128], Vs[128 * 64], Ps[64 * 64];
  int qbase = qt * 64;

  { // stage Q once (swizzled source, linear LDS)
    int row = tid >> 4, sl = tid & 15;
    int slg = sl ^ (row & 7);
    const unsigned short* qg = qkv + (size_t)(qbase + row) * QKVW + head * HD + slg * 8;
#pragma unroll
    for (int j = 0; j < 4; ++j)
      gload16(qg + (size_t)(j * 16) * QKVW, &Qs[(j * 256 + tid) * 8]);
  }

  float mrun[4], lrun[4];
  f4 oacc[8];
#pragma unroll
  for (int j = 0; j < 4; ++j) { mrun[j] = -1e30f; lrun[j] = 0.f; }
#pragma unroll
  for (int n = 0; n < 8; ++n) oacc[n] = (f4){0.f, 0.f, 0.f, 0.f};
  bf8 qf[4];

  for (int kt = 0; kt < SEQ / 64; ++kt) {
    __syncthreads();
    { // stage K tile [64][128]
      int rloc = tid >> 4, sl = tid & 15, slg = sl ^ (rloc & 7);
      const unsigned short* kg =
          qkv + HID + (size_t)(kt * 64 + rloc) * QKVW + head * HD + slg * 8;
#pragma unroll
      for (int j = 0; j < 4; ++j) gload16(kg + (size_t)(j * 16) * QKVW, &Ks[(j * 256 + tid) * 8]);
    }
    { // stage V^T tile [128][64]
      int rloc = tid >> 3, sl = tid & 7, slg = sl ^ (rloc & 7);
      const unsigned short* vg = vt + (size_t)(head * HD + rloc) * SEQ + kt * 64 + slg * 8;
#pragma unroll
      for (int j = 0; j < 4; ++j) gload16(vg + (size_t)(j * 32) * SEQ, &Vs[(j * 256 + tid) * 8]);
    }
    __syncthreads();
    if (kt == 0) {
#pragma unroll
      for (int kk = 0; kk < 4; ++kk) {
        int row = wv * 16 + (lane & 15);
        int col = (kk * 32 + ((lane >> 4) * 8)) ^ ((lane & 7) << 3);
        qf[kk] = *(const bf8*)&Qs[row * 128 + col];
      }
    }
    // QK^T -> sacc[n] : S[16q][64k] per wave
    f4 sacc[4];
#pragma unroll
    for (int n = 0; n < 4; ++n) sacc[n] = (f4){0.f, 0.f, 0.f, 0.f};
#pragma unroll
    for (int kk = 0; kk < 4; ++kk) {
#pragma unroll
      for (int n = 0; n < 4; ++n) {
        int row = n * 16 + (lane & 15);
        int col = (kk * 32 + ((lane >> 4) * 8)) ^ ((lane & 7) << 3);
        bf8 kf = *(const bf8*)&Ks[row * 128 + col];
        sacc[n] = mfma16(qf[kk], kf, sacc[n]);
      }
    }
    const float SC = 0.08838834764831845f;
    float mj[4];
#pragma unroll
    for (int j = 0; j < 4; ++j)
      mj[j] = fmaxf(fmaxf(sacc[0][j], sacc[1][j]), fmaxf(sacc[2][j], sacc[3][j]));
#pragma unroll
    for (int j = 0; j < 4; ++j) {
#pragma unroll
      for (int mk = 8; mk; mk >>= 1) mj[j] = fmaxf(mj[j], __shfl_xor(mj[j], mk));
    }
    float resc[4], psum[4];
#pragma unroll
    for (int j = 0; j < 4; ++j) {
      float nm = fmaxf(mrun[j], mj[j] * SC);
      resc[j] = __expf(mrun[j] - nm);
      mrun[j] = nm;
      psum[j] = 0.f;
    }
#pragma unroll
    for (int n = 0; n < 4; ++n) {
#pragma unroll
      for (int j = 0; j < 4; ++j) {
        float p = __expf(sacc[n][j] * SC - mrun[j]);
        psum[j] += p;
        int row = wv * 16 + ((lane >> 4) << 2) + j;
        int col = (n * 16 + (lane & 15)) ^ ((row & 7) << 3);
        Ps[row * 64 + col] = f2bf(p);
      }
    }
#pragma unroll
    for (int j = 0; j < 4; ++j) {
#pragma unroll
      for (int mk = 8; mk; mk >>= 1) psum[j] += __shfl_xor(psum[j], mk);
      lrun[j] = lrun[j] * resc[j] + psum[j];
    }
#pragma unroll
    for (int n = 0; n < 8; ++n) {
#pragma unroll
      for (int j = 0; j < 4; ++j) oacc[n][j] *= resc[j];
    }
    // PV
#pragma unroll
    for (int kk = 0; kk < 2; ++kk) {
      int prow = wv * 16 + (lane & 15);
      int pcol = (kk * 32 + ((lane >> 4) * 8)) ^ ((lane & 7) << 3);
      bf8 pa = *(const bf8*)&Ps[prow * 64 + pcol];
#pragma unroll
      for (int n = 0; n < 8; ++n) {
        int vrow = n * 16 + (lane & 15);
        int vcol = (kk * 32 + ((lane >> 4) * 8)) ^ ((vrow & 7) << 3);
        bf8 vf = *(const bf8*)&Vs[vrow * 64 + vcol];
        oacc[n] = mfma16(pa, vf, oacc[n]);
      }
    }
  }
  // epilogue: O /= l, write bf16 into attnmlp cols [0,3072)
#pragma unroll
  for (int j = 0; j < 4; ++j) {
    float invl = 1.f / lrun[j];
    int row = qbase + wv * 16 + ((lane >> 4) << 2) + j;
#pragma unroll
    for (int n = 0; n < 8; ++n) {
      int col = head * HD + n * 16 + (lane & 15);
      amlp[(size_t)row * N2CAT + col] = f2bf(oacc[n][j] * invl);
    }
  }
}

extern "C" void kernel_launch(void* const* d_in, const int* in_sizes, int n_in,
                              void* d_out, int out_size, void* d_ws, size_t ws_size,
                              hipStream_t stream) {
  (void)in_sizes; (void)n_in; (void)out_size; (void)ws_size;
  const float* img  = (const float*)d_in[0];
  const float* txt  = (const float*)d_in[1];
  const float* vec  = (const float*)d_in[2];
  const float* fcos = (const float*)d_in[3];
  const float* fsin = (const float*)d_in[4];
  const float* w1   = (const float*)d_in[5];
  const float* b1   = (const float*)d_in[6];
  const float* w2   = (const float*)d_in[7];
  const float* b2   = (const float*)d_in[8];
  const float* qnw  = (const float*)d_in[9];
  const float* knw  = (const float*)d_in[10];
  const float* mw   = (const float*)d_in[11];
  const float* mb   = (const float*)d_in[12];
  float* out = (float*)d_out;

  char* ws = (char*)d_ws;
  float*          mod  = (float*)(ws);                          // 36,864 B
  unsigned short* xmod = (unsigned short*)(ws + 40960);         // 14,155,776 B
  unsigned short* w1b  = (unsigned short*)(ws + 14196736);      // 132,120,576 B
  unsigned short* qkv  = (unsigned short*)(ws + 146317312);     // 42,467,328 B
  unsigned short* amlp = (unsigned short*)(ws + 188784640);     // 70,778,880 B (end ~259.6MB)
  unsigned short* vtb  = xmod;   // x_mod dead after GEMM1
  unsigned short* w2b  = w1b;    // w1 bf16 dead after GEMM1

  k_mod<<<QKVW / 4, 256, 0, stream>>>(vec, mw, mb, mod);
  k_lnmod<<<SEQ, 256, 0, stream>>>(img, txt, mod, xmod);
  k_f2bf<<<2048, 256, 0, stream>>>(w1, w1b, N1 * HID / 4);
  k_gemm1<<<756, 512, 0, stream>>>(xmod, w1b, b1, qkv, amlp);
  k_qknorm<<<SEQ * NHEAD / 4, 256, 0, stream>>>(qkv, qnw, knw, fcos, fsin);
  k_vt<<<NHEAD * 36 * 2, 256, 0, stream>>>(qkv, vtb);
  k_f2bf<<<2048, 256, 0, stream>>>(w2, w2b, HID * N2CAT / 4);
  k_attn<<<864, 256, 0, stream>>>(qkv, vtb, amlp);
  k_gemm2<<<18 * 24, 256, 0, stream>>>(amlp, w2b, b2, img, txt, mod + 2 * HID, out);
}

// Round 4
// 983.838 us; speedup vs baseline: 1.1152x; 1.0481x over previous
//
#include <hip/hip_runtime.h>
#include <hip/hip_bf16.h>

#define DI __device__ __forceinline__

typedef __attribute__((ext_vector_type(8))) short bf8;
typedef __attribute__((ext_vector_type(4))) float f4;
typedef __attribute__((ext_vector_type(8))) unsigned short us8;

#define LI    2048
#define LT    256
#define SEQ   2304
#define HID   3072
#define NHEAD 24
#define HD    128
#define N1    21504      // 3*HID + MLP
#define QKVW  9216       // 3*HID
#define N2CAT 15360      // HID + MLP

DI unsigned short f2bf(float f) {
  union { float f; unsigned u; } v; v.f = f;
  unsigned r = v.u + 0x7FFFu + ((v.u >> 16) & 1u);
  return (unsigned short)(r >> 16);
}
DI float bf2f(unsigned short h) {
  union { unsigned u; float f; } v; v.u = ((unsigned)h) << 16;
  return v.f;
}

DI void gload16(const void* g, void* l) {
  __builtin_amdgcn_global_load_lds(
      (const __attribute__((address_space(1))) void*)g,
      (__attribute__((address_space(3))) void*)l, 16, 0, 0);
}

DI f4 mfma16(bf8 a, bf8 b, f4 c) {
  return __builtin_amdgcn_mfma_f32_16x16x32_bf16(a, b, c, 0, 0, 0);
}

// ---------------- modulation GEMV: mod = silu(vec) @ mod_w^T + mod_b ----------------
__global__ void k_mod(const float* __restrict__ vec, const float* __restrict__ mw,
                      const float* __restrict__ mb, float* __restrict__ mod) {
  int row = blockIdx.x * 4 + (threadIdx.x >> 6);
  int lane = threadIdx.x & 63;
  const float4* wr = (const float4*)(mw + (size_t)row * HID);
  const float4* vv = (const float4*)vec;
  float s = 0.f;
  for (int i = lane; i < HID / 4; i += 64) {
    float4 w4 = wr[i], x4 = vv[i];
    s += (x4.x / (1.f + __expf(-x4.x))) * w4.x;
    s += (x4.y / (1.f + __expf(-x4.y))) * w4.y;
    s += (x4.z / (1.f + __expf(-x4.z))) * w4.z;
    s += (x4.w / (1.f + __expf(-x4.w))) * w4.w;
  }
#pragma unroll
  for (int m = 32; m; m >>= 1) s += __shfl_xor(s, m);
  if (lane == 0) mod[row] = s + mb[row];
}

// ---------------- layernorm + modulate -> x_mod (bf16) ----------------
__global__ void k_lnmod(const float* __restrict__ img, const float* __restrict__ txt,
                        const float* __restrict__ mod, unsigned short* __restrict__ xmod) {
  int t = blockIdx.x;
  const float* x = (t < LI) ? (img + (size_t)t * HID) : (txt + (size_t)(t - LI) * HID);
  const float4* x4 = (const float4*)x;
  float4 v[3];
  float s = 0.f, ss = 0.f;
#pragma unroll
  for (int j = 0; j < 3; ++j) {
    v[j] = x4[threadIdx.x + j * 256];
    s  += v[j].x + v[j].y + v[j].z + v[j].w;
    ss += v[j].x * v[j].x + v[j].y * v[j].y + v[j].z * v[j].z + v[j].w * v[j].w;
  }
#pragma unroll
  for (int m = 32; m; m >>= 1) { s += __shfl_xor(s, m); ss += __shfl_xor(ss, m); }
  __shared__ float red[8];
  int wv = threadIdx.x >> 6;
  if ((threadIdx.x & 63) == 0) { red[wv] = s; red[4 + wv] = ss; }
  __syncthreads();
  s = red[0] + red[1] + red[2] + red[3];
  ss = red[4] + red[5] + red[6] + red[7];
  float mu = s * (1.f / HID);
  float var = ss * (1.f / HID) - mu * mu;
  float inv = rsqrtf(var + 1e-6f);
  const float* shift = mod;
  const float* scale = mod + HID;
#pragma unroll
  for (int j = 0; j < 3; ++j) {
    int i = threadIdx.x + j * 256;
    int c = i * 4;
    ushort4 o;
    o.x = f2bf((v[j].x - mu) * inv * (1.f + scale[c + 0]) + shift[c + 0]);
    o.y = f2bf((v[j].y - mu) * inv * (1.f + scale[c + 1]) + shift[c + 1]);
    o.z = f2bf((v[j].z - mu) * inv * (1.f + scale[c + 2]) + shift[c + 2]);
    o.w = f2bf((v[j].w - mu) * inv * (1.f + scale[c + 3]) + shift[c + 3]);
    ((ushort4*)xmod)[(size_t)t * (HID / 4) + i] = o;
  }
}

// ---------------- f32 -> bf16 bulk convert ----------------
__global__ void k_f2bf(const float* __restrict__ in, unsigned short* __restrict__ out, int n4) {
  int stride = gridDim.x * blockDim.x;
  for (int i = blockIdx.x * blockDim.x + threadIdx.x; i < n4; i += stride) {
    float4 f = ((const float4*)in)[i];
    ushort4 o;
    o.x = f2bf(f.x); o.y = f2bf(f.y); o.z = f2bf(f.z); o.w = f2bf(f.w);
    ((ushort4*)out)[i] = o;
  }
}

// ================= GEMM1: 256x256 tile, BK=64, 8-wave, fine-interleaved 4-phase/K-tile ===========
// Per phase: {few ds_read_b128 || 1 half-tile global_load_lds || 16 MFMA}; counted vmcnt(2)
// once per K-tile at ph3 end (before the barrier). Never vmcnt(0) in the loop.
#define BAR()    asm volatile("s_barrier" ::: "memory")
#define VMCNT2() asm volatile("s_waitcnt vmcnt(2)" ::: "memory")
#define VMCNT0() asm volatile("s_waitcnt vmcnt(0)" ::: "memory")
#define LGKM0()  do { asm volatile("s_waitcnt lgkmcnt(0)" ::: "memory"); \
                      __builtin_amdgcn_sched_barrier(0); } while (0)

__global__ __launch_bounds__(512, 2) void k_gemm1(const unsigned short* __restrict__ xmod,
    const unsigned short* __restrict__ w1b, const float* __restrict__ b1,
    unsigned short* __restrict__ qkv, unsigned short* __restrict__ amlp) {
  __shared__ unsigned short As[2][256 * 64];
  __shared__ unsigned short Bs[2][256 * 64];
  const int K = HID;          // 3072
  const int NT = K / 64;      // 48 K-tiles
  int tid = threadIdx.x, lane = tid & 63, wid = tid >> 6;
  int wr = wid >> 2, wc = wid & 3;

  // bijective XCD swizzle (nwg=756: q=94, r=4)
  int b = blockIdx.x;
  const int Q = 756 / 8, R = 756 % 8;
  int xcd = b & 7, idx = b >> 3;
  int wg = (xcd < R ? xcd * (Q + 1) : R * (Q + 1) + (xcd - R) * Q) + idx;
  int bm = wg % 9, bn = wg / 9;

  const unsigned short* Ag = xmod + (size_t)bm * 256 * K;
  const unsigned short* Bg = w1b + (size_t)bn * 256 * K;

  int sgran = (lane & 7) ^ ((lane >> 3) & 7);
  int srow = wid * 16 + (lane >> 3);

#define STAGE_A(bufi, t, hh) do { \
    gload16(Ag + (size_t)((hh)*128 + srow) * K + (t)*64 + sgran*8, \
            &As[bufi][((hh)*128 + wid*16) * 64]); \
    gload16(Ag + (size_t)((hh)*128 + 8 + srow) * K + (t)*64 + sgran*8, \
            &As[bufi][((hh)*128 + wid*16 + 8) * 64]); \
  } while (0)
#define STAGE_B(bufi, t, hh) do { \
    gload16(Bg + (size_t)((hh)*128 + srow) * K + (t)*64 + sgran*8, \
            &Bs[bufi][((hh)*128 + wid*16) * 64]); \
    gload16(Bg + (size_t)((hh)*128 + 8 + srow) * K + (t)*64 + sgran*8, \
            &Bs[bufi][((hh)*128 + wid*16 + 8) * 64]); \
  } while (0)

  int rA = wr * 128 + (lane & 15);
  int rB = wc * 64 + (lane & 15);
  int qq = lane >> 4, l7 = lane & 7;

  f4 acc[8][4];
#pragma unroll
  for (int m = 0; m < 8; ++m)
#pragma unroll
    for (int n = 0; n < 4; ++n) acc[m][n] = (f4){0.f, 0.f, 0.f, 0.f};
  bf8 aL[4][2], aH[4][2], bL[2][2], bH[2][2];

#define RD(buf, r, s) (*(const bf8*)&buf[(r) * 64 + ((((s)*4 + qq) ^ l7) << 3)])

  // GROUP = one K-tile (4 phases). C = LDS buffer (compile-time), tt = this tile,
  // tn = tile staged into buf 1-C (halves A1,B0,B1), tn2 = tile whose A0 goes into buf C.
#define GROUP(C, tt, tn, tn2) do { \
    /* ph0: a_lo + b_lo reads, stage (tn).A1, MFMA quadrant (0,0) */ \
    _Pragma("unroll") for (int m = 0; m < 4; ++m) \
      _Pragma("unroll") for (int s = 0; s < 2; ++s) aL[m][s] = RD(As[C], rA + m*16, s); \
    _Pragma("unroll") for (int n = 0; n < 2; ++n) \
      _Pragma("unroll") for (int s = 0; s < 2; ++s) bL[n][s] = RD(Bs[C], rB + n*16, s); \
    STAGE_A(1-(C), tn, 1); \
    LGKM0(); \
    __builtin_amdgcn_s_setprio(1); \
    _Pragma("unroll") for (int m = 0; m < 4; ++m) \
      _Pragma("unroll") for (int n = 0; n < 2; ++n) \
        _Pragma("unroll") for (int s = 0; s < 2; ++s) \
          acc[m][n] = mfma16(aL[m][s], bL[n][s], acc[m][n]); \
    __builtin_amdgcn_s_setprio(0); \
    BAR(); \
    /* ph1: b_hi reads, stage (tn).B0, MFMA quadrant (0,1) */ \
    _Pragma("unroll") for (int n = 0; n < 2; ++n) \
      _Pragma("unroll") for (int s = 0; s < 2; ++s) bH[n][s] = RD(Bs[C], rB + (n+2)*16, s); \
    STAGE_B(1-(C), tn, 0); \
    LGKM0(); \
    __builtin_amdgcn_s_setprio(1); \
    _Pragma("unroll") for (int m = 0; m < 4; ++m) \
      _Pragma("unroll") for (int n = 0; n < 2; ++n) \
        _Pragma("unroll") for (int s = 0; s < 2; ++s) \
          acc[m][n+2] = mfma16(aL[m][s], bH[n][s], acc[m][n+2]); \
    __builtin_amdgcn_s_setprio(0); \
    BAR(); \
    /* ph2: a_hi reads, stage (tn).B1, MFMA quadrant (1,1) */ \
    _Pragma("unroll") for (int m = 0; m < 4; ++m) \
      _Pragma("unroll") for (int s = 0; s < 2; ++s) aH[m][s] = RD(As[C], rA + (m+4)*16, s); \
    STAGE_B(1-(C), tn, 1); \
    LGKM0(); \
    __builtin_amdgcn_s_setprio(1); \
    _Pragma("unroll") for (int m = 0; m < 4; ++m) \
      _Pragma("unroll") for (int n = 0; n < 2; ++n) \
        _Pragma("unroll") for (int s = 0; s < 2; ++s) \
          acc[m+4][n+2] = mfma16(aH[m][s], bH[n][s], acc[m+4][n+2]); \
    __builtin_amdgcn_s_setprio(0); \
    BAR(); \
    /* ph3: no reads, stage (tn2).A0 into just-freed buf C, MFMA quadrant (1,0) */ \
    STAGE_A(C, tn2, 0); \
    __builtin_amdgcn_s_setprio(1); \
    _Pragma("unroll") for (int m = 0; m < 4; ++m) \
      _Pragma("unroll") for (int n = 0; n < 2; ++n) \
        _Pragma("unroll") for (int s = 0; s < 2; ++s) \
          acc[m+4][n] = mfma16(aH[m][s], bL[n][s], acc[m+4][n]); \
    __builtin_amdgcn_s_setprio(0); \
    VMCNT2();   /* completes tile tn fully; leaves (tn2).A0 in flight */ \
    BAR(); \
  } while (0)

  // prologue: tile0 fully + tile1.A0; vmcnt(2) completes tile0, leaves tile1.A0
  STAGE_A(0, 0, 0); STAGE_A(0, 0, 1); STAGE_B(0, 0, 0); STAGE_B(0, 0, 1);
  STAGE_A(1, 1, 0);
  VMCNT2();
  BAR();

  for (int i = 0; i < NT / 2; ++i) {
    int t0 = 2 * i, t1 = 2 * i + 1;
    int n1 = t0 + 2; if (n1 > NT - 1) n1 = NT - 1;
    int n2 = t0 + 3; if (n2 > NT - 1) n2 = NT - 1;
    GROUP(0, t0, t0 + 1, n1);
    GROUP(1, t1, n1, n2);
  }
  VMCNT0();   // drain async LDS writes before block exit

  // epilogue: bias + qkv/gelu split
  int r0 = bm * 256 + wr * 128 + ((lane >> 4) << 2);
  int c0 = bn * 256 + wc * 64 + (lane & 15);
  bool isqkv = (bn * 256) < QKVW;
#pragma unroll
  for (int m = 0; m < 8; ++m) {
#pragma unroll
    for (int n = 0; n < 4; ++n) {
      int col = c0 + n * 16;
      float bias = b1[col];
#pragma unroll
      for (int j = 0; j < 4; ++j) {
        int row = r0 + m * 16 + j;
        float v = acc[m][n][j] + bias;
        if (isqkv) {
          qkv[(size_t)row * QKVW + col] = f2bf(v);
        } else {
          float u = 0.7978845608f * (v + 0.044715f * v * v * v);
          float g = v / (1.f + __expf(-2.f * u));
          amlp[(size_t)row * N2CAT + (col - 6144)] = f2bf(g);
        }
      }
    }
  }
#undef STAGE_A
#undef STAGE_B
#undef RD
#undef GROUP
}

// ---------------- shared 128x128 GEMM mainloop (used by gemm2) ----------------
DI void gemm_core(const unsigned short* __restrict__ A, const unsigned short* __restrict__ Bw,
                  int K, int bm, int bn, unsigned short* As, unsigned short* Bs, f4 acc[4][4]) {
  int tid = threadIdx.x;
  int lane = tid & 63;
  int wr = (tid >> 7) & 1;
  int wc = (tid >> 6) & 1;
#pragma unroll
  for (int m = 0; m < 4; ++m)
#pragma unroll
    for (int n = 0; n < 4; ++n) acc[m][n] = (f4){0.f, 0.f, 0.f, 0.f};

  int rbase = tid >> 3;
  int slg = (tid & 7) ^ (rbase & 7);
  const unsigned short* Ag = A + (size_t)(bm * 128 + rbase) * K + slg * 8;
  const unsigned short* Bg = Bw + (size_t)(bn * 128 + rbase) * K + slg * 8;
  unsigned short* Asd = As + tid * 8;
  unsigned short* Bsd = Bs + tid * 8;

  int rA = wr * 64 + (lane & 15);
  int rB = wc * 64 + (lane & 15);
  int cb = (lane >> 4) * 8;
  int cx = (lane & 7) << 3;

  for (int k0 = 0; k0 < K; k0 += 64) {
    __syncthreads();
#pragma unroll
    for (int j = 0; j < 4; ++j) {
      gload16(Ag + (size_t)(j * 32) * K + k0, Asd + j * 2048);
      gload16(Bg + (size_t)(j * 32) * K + k0, Bsd + j * 2048);
    }
    __syncthreads();
#pragma unroll
    for (int kk = 0; kk < 2; ++kk) {
      bf8 av[4], bv[4];
#pragma unroll
      for (int m = 0; m < 4; ++m)
        av[m] = *(const bf8*)&As[(rA + m * 16) * 64 + ((kk * 32 + cb) ^ cx)];
#pragma unroll
      for (int n = 0; n < 4; ++n)
        bv[n] = *(const bf8*)&Bs[(rB + n * 16) * 64 + ((kk * 32 + cb) ^ cx)];
#pragma unroll
      for (int m = 0; m < 4; ++m)
#pragma unroll
        for (int n = 0; n < 4; ++n)
          acc[m][n] = mfma16(av[m], bv[n], acc[m][n]);
    }
  }
}

// ---------------- GEMM2: [attn|mlp] @ w2^T + b2, gated residual -> f32 out ----------------
__global__ __launch_bounds__(256) void k_gemm2(const unsigned short* __restrict__ amlp,
    const unsigned short* __restrict__ w2b, const float* __restrict__ b2,
    const float* __restrict__ img, const float* __restrict__ txt,
    const float* __restrict__ gate, float* __restrict__ out) {
  __shared__ unsigned short As[128 * 64], Bs[128 * 64];
  int nb = gridDim.x;
  int b = blockIdx.x;
  int bsw = (b & 7) * (nb >> 3) + (b >> 3);
  int bm = bsw % 18, bn = bsw / 18;
  f4 acc[4][4];
  gemm_core(amlp, w2b, N2CAT, bm, bn, As, Bs, acc);
  int lane = threadIdx.x & 63;
  int wr = (threadIdx.x >> 7) & 1, wc = (threadIdx.x >> 6) & 1;
  int r0 = bm * 128 + wr * 64 + ((lane >> 4) << 2);
  int c0 = bn * 128 + wc * 64 + (lane & 15);
#pragma unroll
  for (int m = 0; m < 4; ++m) {
#pragma unroll
    for (int n = 0; n < 4; ++n) {
      int col = c0 + n * 16;
      float bias = b2[col];
      float gt = gate[col];
#pragma unroll
      for (int j = 0; j < 4; ++j) {
        int row = r0 + m * 16 + j;
        float v = acc[m][n][j] + bias;
        float res = (row < LI) ? img[(size_t)row * HID + col]
                               : txt[(size_t)(row - LI) * HID + col];
        out[(size_t)row * HID + col] = res + gt * v;
      }
    }
  }
}

// ---------------- per-(token,head) RMSNorm + RoPE on q,k (in place, bf16) ----------------
__global__ void k_qknorm(unsigned short* __restrict__ qkv, const float* __restrict__ qw,
                         const float* __restrict__ kw, const float* __restrict__ fcos,
                         const float* __restrict__ fsin) {
  int gw = (blockIdx.x * 256 + threadIdx.x) >> 6;
  int lane = threadIdx.x & 63;
  int token = gw / NHEAD, head = gw - token * NHEAD;
  bool dorope = token < LI;
  float c = 1.f, sn = 0.f;
  if (dorope) { c = fcos[token * HD + 2 * lane]; sn = fsin[token * HD + 2 * lane]; }
#pragma unroll
  for (int qk = 0; qk < 2; ++qk) {
    unsigned short* p = qkv + (size_t)token * QKVW + qk * HID + head * HD;
    unsigned u = ((const unsigned*)p)[lane];
    float x0 = bf2f((unsigned short)(u & 0xffff));
    float x1 = bf2f((unsigned short)(u >> 16));
    float ss = x0 * x0 + x1 * x1;
#pragma unroll
    for (int m2 = 32; m2; m2 >>= 1) ss += __shfl_xor(ss, m2);
    float inv = rsqrtf(ss * (1.f / HD) + 1e-6f);
    const float* w = qk ? kw : qw;
    float y0 = x0 * inv * w[2 * lane];
    float y1 = x1 * inv * w[2 * lane + 1];
    if (dorope) { float r0 = y0 * c - y1 * sn; float r1 = y1 * c + y0 * sn; y0 = r0; y1 = r1; }
    ((unsigned*)p)[lane] = ((unsigned)f2bf(y0)) | (((unsigned)f2bf(y1)) << 16);
  }
}

// ---------------- transpose V: qkv v-slice [S][24*128] -> vt [24][128][S] ----------------
__global__ void k_vt(const unsigned short* __restrict__ qkv, unsigned short* __restrict__ vt) {
  int b = blockIdx.x;                 // 24*36*2
  int h = b / 72; int rem = b - h * 72; int tt = rem >> 1; int dd = rem & 1;
  int t0 = tt * 64, d0 = dd * 64;
  __shared__ unsigned short tile[64 * 65];
  int tid = threadIdx.x;
#pragma unroll
  for (int j = 0; j < 2; ++j) {
    int idx = j * 256 + tid;
    int row = idx >> 3, s = idx & 7;
    us8 vv = *(const us8*)(qkv + (size_t)(t0 + row) * QKVW + 2 * HID + h * HD + d0 + s * 8);
#pragma unroll
    for (int i = 0; i < 8; ++i) tile[row * 65 + s * 8 + i] = vv[i];
  }
  __syncthreads();
#pragma unroll
  for (int j = 0; j < 2; ++j) {
    int idx = j * 256 + tid;
    int dr = idx >> 3, sl = idx & 7;
    us8 o;
#pragma unroll
    for (int i = 0; i < 8; ++i) o[i] = tile[(sl * 8 + i) * 65 + dr];
    *(us8*)(vt + (size_t)(h * HD + d0 + dr) * SEQ + t0 + sl * 8) = o;
  }
}

// ---------------- flash attention: 64-row Q tile per block, 4 waves, online softmax ----------------
__global__ __launch_bounds__(256) void k_attn(const unsigned short* __restrict__ qkv,
                                              const unsigned short* __restrict__ vt,
                                              unsigned short* __restrict__ amlp) {
  int b = blockIdx.x;                           // 864 = 24 heads * 36 qtiles
  int bsw = (b & 7) * 108 + (b >> 3);
  int head = bsw / 36, qt = bsw - head * 36;
  int tid = threadIdx.x, lane = tid & 63, wv = tid >> 6;
  __shared__ unsigned short Qs[64 * 128], Ks[64 * 128], Vs[128 * 64], Ps[64 * 64];
  int qbase = qt * 64;

  { // stage Q once (swizzled source, linear LDS)
    int row = tid >> 4, sl = tid & 15;
    int slg = sl ^ (row & 7);
    const unsigned short* qg = qkv + (size_t)(qbase + row) * QKVW + head * HD + slg * 8;
#pragma unroll
    for (int j = 0; j < 4; ++j)
      gload16(qg + (size_t)(j * 16) * QKVW, &Qs[(j * 256 + tid) * 8]);
  }

  float mrun[4], lrun[4];
  f4 oacc[8];
#pragma unroll
  for (int j = 0; j < 4; ++j) { mrun[j] = -1e30f; lrun[j] = 0.f; }
#pragma unroll
  for (int n = 0; n < 8; ++n) oacc[n] = (f4){0.f, 0.f, 0.f, 0.f};
  bf8 qf[4];

  for (int kt = 0; kt < SEQ / 64; ++kt) {
    __syncthreads();
    { // stage K tile [64][128]
      int rloc = tid >> 4, sl = tid & 15, slg = sl ^ (rloc & 7);
      const unsigned short* kg =
          qkv + HID + (size_t)(kt * 64 + rloc) * QKVW + head * HD + slg * 8;
#pragma unroll
      for (int j = 0; j < 4; ++j) gload16(kg + (size_t)(j * 16) * QKVW, &Ks[(j * 256 + tid) * 8]);
    }
    { // stage V^T tile [128][64]
      int rloc = tid >> 3, sl = tid & 7, slg = sl ^ (rloc & 7);
      const unsigned short* vg = vt + (size_t)(head * HD + rloc) * SEQ + kt * 64 + slg * 8;
#pragma unroll
      for (int j = 0; j < 4; ++j) gload16(vg + (size_t)(j * 32) * SEQ, &Vs[(j * 256 + tid) * 8]);
    }
    __syncthreads();
    if (kt == 0) {
#pragma unroll
      for (int kk = 0; kk < 4; ++kk) {
        int row = wv * 16 + (lane & 15);
        int col = (kk * 32 + ((lane >> 4) * 8)) ^ ((lane & 7) << 3);
        qf[kk] = *(const bf8*)&Qs[row * 128 + col];
      }
    }
    // QK^T -> sacc[n] : S[16q][64k] per wave
    f4 sacc[4];
#pragma unroll
    for (int n = 0; n < 4; ++n) sacc[n] = (f4){0.f, 0.f, 0.f, 0.f};
#pragma unroll
    for (int kk = 0; kk < 4; ++kk) {
#pragma unroll
      for (int n = 0; n < 4; ++n) {
        int row = n * 16 + (lane & 15);
        int col = (kk * 32 + ((lane >> 4) * 8)) ^ ((lane & 7) << 3);
        bf8 kf = *(const bf8*)&Ks[row * 128 + col];
        sacc[n] = mfma16(qf[kk], kf, sacc[n]);
      }
    }
    const float SC = 0.08838834764831845f;
    float mj[4];
#pragma unroll
    for (int j = 0; j < 4; ++j)
      mj[j] = fmaxf(fmaxf(sacc[0][j], sacc[1][j]), fmaxf(sacc[2][j], sacc[3][j]));
#pragma unroll
    for (int j = 0; j < 4; ++j) {
#pragma unroll
      for (int mk = 8; mk; mk >>= 1) mj[j] = fmaxf(mj[j], __shfl_xor(mj[j], mk));
    }
    float resc[4], psum[4];
#pragma unroll
    for (int j = 0; j < 4; ++j) {
      float nm = fmaxf(mrun[j], mj[j] * SC);
      resc[j] = __expf(mrun[j] - nm);
      mrun[j] = nm;
      psum[j] = 0.f;
    }
#pragma unroll
    for (int n = 0; n < 4; ++n) {
#pragma unroll
      for (int j = 0; j < 4; ++j) {
        float p = __expf(sacc[n][j] * SC - mrun[j]);
        psum[j] += p;
        int row = wv * 16 + ((lane >> 4) << 2) + j;
        int col = (n * 16 + (lane & 15)) ^ ((row & 7) << 3);
        Ps[row * 64 + col] = f2bf(p);
      }
    }
#pragma unroll
    for (int j = 0; j < 4; ++j) {
#pragma unroll
      for (int mk = 8; mk; mk >>= 1) psum[j] += __shfl_xor(psum[j], mk);
      lrun[j] = lrun[j] * resc[j] + psum[j];
    }
#pragma unroll
    for (int n = 0; n < 8; ++n) {
#pragma unroll
      for (int j = 0; j < 4; ++j) oacc[n][j] *= resc[j];
    }
    // PV
#pragma unroll
    for (int kk = 0; kk < 2; ++kk) {
      int prow = wv * 16 + (lane & 15);
      int pcol = (kk * 32 + ((lane >> 4) * 8)) ^ ((lane & 7) << 3);
      bf8 pa = *(const bf8*)&Ps[prow * 64 + pcol];
#pragma unroll
      for (int n = 0; n < 8; ++n) {
        int vrow = n * 16 + (lane & 15);
        int vcol = (kk * 32 + ((lane >> 4) * 8)) ^ ((vrow & 7) << 3);
        bf8 vf = *(const bf8*)&Vs[vrow * 64 + vcol];
        oacc[n] = mfma16(pa, vf, oacc[n]);
      }
    }
  }
  // epilogue: O /= l, write bf16 into attnmlp cols [0,3072)
#pragma unroll
  for (int j = 0; j < 4; ++j) {
    float invl = 1.f / lrun[j];
    int row = qbase + wv * 16 + ((lane >> 4) << 2) + j;
#pragma unroll
    for (int n = 0; n < 8; ++n) {
      int col = head * HD + n * 16 + (lane & 15);
      amlp[(size_t)row * N2CAT + col] = f2bf(oacc[n][j] * invl);
    }
  }
}

extern "C" void kernel_launch(void* const* d_in, const int* in_sizes, int n_in,
                              void* d_out, int out_size, void* d_ws, size_t ws_size,
                              hipStream_t stream) {
  (void)in_sizes; (void)n_in; (void)out_size; (void)ws_size;
  const float* img  = (const float*)d_in[0];
  const float* txt  = (const float*)d_in[1];
  const float* vec  = (const float*)d_in[2];
  const float* fcos = (const float*)d_in[3];
  const float* fsin = (const float*)d_in[4];
  const float* w1   = (const float*)d_in[5];
  const float* b1   = (const float*)d_in[6];
  const float* w2   = (const float*)d_in[7];
  const float* b2   = (const float*)d_in[8];
  const float* qnw  = (const float*)d_in[9];
  const float* knw  = (const float*)d_in[10];
  const float* mw   = (const float*)d_in[11];
  const float* mb   = (const float*)d_in[12];
  float* out = (float*)d_out;

  char* ws = (char*)d_ws;
  float*          mod  = (float*)(ws);                          // 36,864 B
  unsigned short* xmod = (unsigned short*)(ws + 40960);         // 14,155,776 B
  unsigned short* w1b  = (unsigned short*)(ws + 14196736);      // 132,120,576 B
  unsigned short* qkv  = (unsigned short*)(ws + 146317312);     // 42,467,328 B
  unsigned short* amlp = (unsigned short*)(ws + 188784640);     // 70,778,880 B (end ~259.6MB)
  unsigned short* vtb  = xmod;   // x_mod dead after GEMM1
  unsigned short* w2b  = w1b;    // w1 bf16 dead after GEMM1

  k_mod<<<QKVW / 4, 256, 0, stream>>>(vec, mw, mb, mod);
  k_lnmod<<<SEQ, 256, 0, stream>>>(img, txt, mod, xmod);
  k_f2bf<<<2048, 256, 0, stream>>>(w1, w1b, N1 * HID / 4);
  k_gemm1<<<756, 512, 0, stream>>>(xmod, w1b, b1, qkv, amlp);
  k_qknorm<<<SEQ * NHEAD / 4, 256, 0, stream>>>(qkv, qnw, knw, fcos, fsin);
  k_vt<<<NHEAD * 36 * 2, 256, 0, stream>>>(qkv, vtb);
  k_f2bf<<<2048, 256, 0, stream>>>(w2, w2b, HID * N2CAT / 4);
  k_attn<<<864, 256, 0, stream>>>(qkv, vtb, amlp);
  k_gemm2<<<18 * 24, 256, 0, stream>>>(amlp, w2b, b2, img, txt, mod + 2 * HID, out);
}

// Round 5
// 965.727 us; speedup vs baseline: 1.1361x; 1.0188x over previous
//
#include <hip/hip_runtime.h>
#include <hip/hip_bf16.h>

#define DI __device__ __forceinline__

typedef __attribute__((ext_vector_type(8))) short bf8;
typedef __attribute__((ext_vector_type(4))) float f4;
typedef __attribute__((ext_vector_type(8))) unsigned short us8;

#define LI    2048
#define LT    256
#define SEQ   2304
#define HID   3072
#define NHEAD 24
#define HD    128
#define N1    21504      // 3*HID + MLP
#define QKVW  9216       // 3*HID
#define N2CAT 15360      // HID + MLP

DI unsigned short f2bf(float f) {
  union { float f; unsigned u; } v; v.f = f;
  unsigned r = v.u + 0x7FFFu + ((v.u >> 16) & 1u);
  return (unsigned short)(r >> 16);
}
DI float bf2f(unsigned short h) {
  union { unsigned u; float f; } v; v.u = ((unsigned)h) << 16;
  return v.f;
}

DI void gload16(const void* g, void* l) {
  __builtin_amdgcn_global_load_lds(
      (const __attribute__((address_space(1))) void*)g,
      (__attribute__((address_space(3))) void*)l, 16, 0, 0);
}

DI f4 mfma16(bf8 a, bf8 b, f4 c) {
  return __builtin_amdgcn_mfma_f32_16x16x32_bf16(a, b, c, 0, 0, 0);
}

// ---------------- modulation GEMV: mod = silu(vec) @ mod_w^T + mod_b ----------------
__global__ void k_mod(const float* __restrict__ vec, const float* __restrict__ mw,
                      const float* __restrict__ mb, float* __restrict__ mod) {
  int row = blockIdx.x * 4 + (threadIdx.x >> 6);
  int lane = threadIdx.x & 63;
  const float4* wr = (const float4*)(mw + (size_t)row * HID);
  const float4* vv = (const float4*)vec;
  float s = 0.f;
  for (int i = lane; i < HID / 4; i += 64) {
    float4 w4 = wr[i], x4 = vv[i];
    s += (x4.x / (1.f + __expf(-x4.x))) * w4.x;
    s += (x4.y / (1.f + __expf(-x4.y))) * w4.y;
    s += (x4.z / (1.f + __expf(-x4.z))) * w4.z;
    s += (x4.w / (1.f + __expf(-x4.w))) * w4.w;
  }
#pragma unroll
  for (int m = 32; m; m >>= 1) s += __shfl_xor(s, m);
  if (lane == 0) mod[row] = s + mb[row];
}

// ---------------- layernorm + modulate -> x_mod (bf16) ----------------
__global__ void k_lnmod(const float* __restrict__ img, const float* __restrict__ txt,
                        const float* __restrict__ mod, unsigned short* __restrict__ xmod) {
  int t = blockIdx.x;
  const float* x = (t < LI) ? (img + (size_t)t * HID) : (txt + (size_t)(t - LI) * HID);
  const float4* x4 = (const float4*)x;
  float4 v[3];
  float s = 0.f, ss = 0.f;
#pragma unroll
  for (int j = 0; j < 3; ++j) {
    v[j] = x4[threadIdx.x + j * 256];
    s  += v[j].x + v[j].y + v[j].z + v[j].w;
    ss += v[j].x * v[j].x + v[j].y * v[j].y + v[j].z * v[j].z + v[j].w * v[j].w;
  }
#pragma unroll
  for (int m = 32; m; m >>= 1) { s += __shfl_xor(s, m); ss += __shfl_xor(ss, m); }
  __shared__ float red[8];
  int wv = threadIdx.x >> 6;
  if ((threadIdx.x & 63) == 0) { red[wv] = s; red[4 + wv] = ss; }
  __syncthreads();
  s = red[0] + red[1] + red[2] + red[3];
  ss = red[4] + red[5] + red[6] + red[7];
  float mu = s * (1.f / HID);
  float var = ss * (1.f / HID) - mu * mu;
  float inv = rsqrtf(var + 1e-6f);
  const float* shift = mod;
  const float* scale = mod + HID;
#pragma unroll
  for (int j = 0; j < 3; ++j) {
    int i = threadIdx.x + j * 256;
    int c = i * 4;
    ushort4 o;
    o.x = f2bf((v[j].x - mu) * inv * (1.f + scale[c + 0]) + shift[c + 0]);
    o.y = f2bf((v[j].y - mu) * inv * (1.f + scale[c + 1]) + shift[c + 1]);
    o.z = f2bf((v[j].z - mu) * inv * (1.f + scale[c + 2]) + shift[c + 2]);
    o.w = f2bf((v[j].w - mu) * inv * (1.f + scale[c + 3]) + shift[c + 3]);
    ((ushort4*)xmod)[(size_t)t * (HID / 4) + i] = o;
  }
}

// ---------------- f32 -> bf16 bulk convert ----------------
__global__ void k_f2bf(const float* __restrict__ in, unsigned short* __restrict__ out, int n4) {
  int stride = gridDim.x * blockDim.x;
  for (int i = blockIdx.x * blockDim.x + threadIdx.x; i < n4; i += stride) {
    float4 f = ((const float4*)in)[i];
    ushort4 o;
    o.x = f2bf(f.x); o.y = f2bf(f.y); o.z = f2bf(f.z); o.w = f2bf(f.w);
    ((ushort4*)out)[i] = o;
  }
}

#define BAR()    asm volatile("s_barrier" ::: "memory")
#define VMCNT6() asm volatile("s_waitcnt vmcnt(6)" ::: "memory")
#define VMCNT2() asm volatile("s_waitcnt vmcnt(2)" ::: "memory")
#define VMCNT0() asm volatile("s_waitcnt vmcnt(0)" ::: "memory")
#define LGKM0()  do { asm volatile("s_waitcnt lgkmcnt(0)" ::: "memory"); \
                      __builtin_amdgcn_sched_barrier(0); } while (0)

// ================= GEMM1: 256x256 tile, BK=64, 8-wave, fine-interleaved 4-phase/K-tile ===========
__global__ __launch_bounds__(512, 2) void k_gemm1(const unsigned short* __restrict__ xmod,
    const unsigned short* __restrict__ w1b, const float* __restrict__ b1,
    unsigned short* __restrict__ qkv, unsigned short* __restrict__ amlp) {
  __shared__ unsigned short As[2][256 * 64];
  __shared__ unsigned short Bs[2][256 * 64];
  const int K = HID;          // 3072
  const int NT = K / 64;      // 48 K-tiles
  int tid = threadIdx.x, lane = tid & 63, wid = tid >> 6;
  int wr = wid >> 2, wc = wid & 3;

  // bijective XCD swizzle (nwg=756: q=94, r=4)
  int b = blockIdx.x;
  const int Q = 756 / 8, R = 756 % 8;
  int xcd = b & 7, idx = b >> 3;
  int wg = (xcd < R ? xcd * (Q + 1) : R * (Q + 1) + (xcd - R) * Q) + idx;
  int bm = wg % 9, bn = wg / 9;

  const unsigned short* Ag = xmod + (size_t)bm * 256 * K;
  const unsigned short* Bg = w1b + (size_t)bn * 256 * K;

  int sgran = (lane & 7) ^ ((lane >> 3) & 7);
  int srow = wid * 16 + (lane >> 3);

#define STAGE_A(bufi, t, hh) do { \
    gload16(Ag + (size_t)((hh)*128 + srow) * K + (t)*64 + sgran*8, \
            &As[bufi][((hh)*128 + wid*16) * 64]); \
    gload16(Ag + (size_t)((hh)*128 + 8 + srow) * K + (t)*64 + sgran*8, \
            &As[bufi][((hh)*128 + wid*16 + 8) * 64]); \
  } while (0)
#define STAGE_B(bufi, t, hh) do { \
    gload16(Bg + (size_t)((hh)*128 + srow) * K + (t)*64 + sgran*8, \
            &Bs[bufi][((hh)*128 + wid*16) * 64]); \
    gload16(Bg + (size_t)((hh)*128 + 8 + srow) * K + (t)*64 + sgran*8, \
            &Bs[bufi][((hh)*128 + wid*16 + 8) * 64]); \
  } while (0)

  int rA = wr * 128 + (lane & 15);
  int rB = wc * 64 + (lane & 15);
  int qq = lane >> 4, l7 = lane & 7;

  f4 acc[8][4];
#pragma unroll
  for (int m = 0; m < 8; ++m)
#pragma unroll
    for (int n = 0; n < 4; ++n) acc[m][n] = (f4){0.f, 0.f, 0.f, 0.f};
  bf8 aL[4][2], aH[4][2], bL[2][2], bH[2][2];

#define RD(buf, r, s) (*(const bf8*)&buf[(r) * 64 + ((((s)*4 + qq) ^ l7) << 3)])

  // GROUP: 4 phases per K-tile. Stage order: ph0 (tn).A1, ph1 (tn).B0+(tn).B1,
  // ph2 none, ph3 (tn2).A0 + vmcnt(2). Newest-waited load issued 2 phases before wait.
#define GROUP(C, tt, tn, tn2) do { \
    _Pragma("unroll") for (int m = 0; m < 4; ++m) \
      _Pragma("unroll") for (int s = 0; s < 2; ++s) aL[m][s] = RD(As[C], rA + m*16, s); \
    _Pragma("unroll") for (int n = 0; n < 2; ++n) \
      _Pragma("unroll") for (int s = 0; s < 2; ++s) bL[n][s] = RD(Bs[C], rB + n*16, s); \
    STAGE_A(1-(C), tn, 1); \
    LGKM0(); \
    __builtin_amdgcn_s_setprio(1); \
    _Pragma("unroll") for (int m = 0; m < 4; ++m) \
      _Pragma("unroll") for (int n = 0; n < 2; ++n) \
        _Pragma("unroll") for (int s = 0; s < 2; ++s) \
          acc[m][n] = mfma16(aL[m][s], bL[n][s], acc[m][n]); \
    __builtin_amdgcn_s_setprio(0); \
    BAR(); \
    _Pragma("unroll") for (int n = 0; n < 2; ++n) \
      _Pragma("unroll") for (int s = 0; s < 2; ++s) bH[n][s] = RD(Bs[C], rB + (n+2)*16, s); \
    STAGE_B(1-(C), tn, 0); \
    STAGE_B(1-(C), tn, 1); \
    LGKM0(); \
    __builtin_amdgcn_s_setprio(1); \
    _Pragma("unroll") for (int m = 0; m < 4; ++m) \
      _Pragma("unroll") for (int n = 0; n < 2; ++n) \
        _Pragma("unroll") for (int s = 0; s < 2; ++s) \
          acc[m][n+2] = mfma16(aL[m][s], bH[n][s], acc[m][n+2]); \
    __builtin_amdgcn_s_setprio(0); \
    BAR(); \
    _Pragma("unroll") for (int m = 0; m < 4; ++m) \
      _Pragma("unroll") for (int s = 0; s < 2; ++s) aH[m][s] = RD(As[C], rA + (m+4)*16, s); \
    LGKM0(); \
    __builtin_amdgcn_s_setprio(1); \
    _Pragma("unroll") for (int m = 0; m < 4; ++m) \
      _Pragma("unroll") for (int n = 0; n < 2; ++n) \
        _Pragma("unroll") for (int s = 0; s < 2; ++s) \
          acc[m+4][n+2] = mfma16(aH[m][s], bH[n][s], acc[m+4][n+2]); \
    __builtin_amdgcn_s_setprio(0); \
    BAR(); \
    STAGE_A(C, tn2, 0); \
    __builtin_amdgcn_s_setprio(1); \
    _Pragma("unroll") for (int m = 0; m < 4; ++m) \
      _Pragma("unroll") for (int n = 0; n < 2; ++n) \
        _Pragma("unroll") for (int s = 0; s < 2; ++s) \
          acc[m+4][n] = mfma16(aH[m][s], bL[n][s], acc[m+4][n]); \
    __builtin_amdgcn_s_setprio(0); \
    VMCNT2(); \
    BAR(); \
  } while (0)

  STAGE_A(0, 0, 0); STAGE_A(0, 0, 1); STAGE_B(0, 0, 0); STAGE_B(0, 0, 1);
  STAGE_A(1, 1, 0);
  VMCNT2();
  BAR();

  for (int i = 0; i < NT / 2; ++i) {
    int t0 = 2 * i, t1 = 2 * i + 1;
    int n1 = t0 + 2; if (n1 > NT - 1) n1 = NT - 1;
    int n2 = t0 + 3; if (n2 > NT - 1) n2 = NT - 1;
    GROUP(0, t0, t0 + 1, n1);
    GROUP(1, t1, n1, n2);
  }
  VMCNT0();

  int r0 = bm * 256 + wr * 128 + ((lane >> 4) << 2);
  int c0 = bn * 256 + wc * 64 + (lane & 15);
  bool isqkv = (bn * 256) < QKVW;
#pragma unroll
  for (int m = 0; m < 8; ++m) {
#pragma unroll
    for (int n = 0; n < 4; ++n) {
      int col = c0 + n * 16;
      float bias = b1[col];
#pragma unroll
      for (int j = 0; j < 4; ++j) {
        int row = r0 + m * 16 + j;
        float v = acc[m][n][j] + bias;
        if (isqkv) {
          qkv[(size_t)row * QKVW + col] = f2bf(v);
        } else {
          float u = 0.7978845608f * (v + 0.044715f * v * v * v);
          float g = v / (1.f + __expf(-2.f * u));
          amlp[(size_t)row * N2CAT + (col - 6144)] = f2bf(g);
        }
      }
    }
  }
#undef STAGE_A
#undef STAGE_B
#undef RD
#undef GROUP
}

// ======== GEMM2: 256x128 tile, BK=64, 8-wave(4x2), 3-deep LDS ring, 4-phase/K-tile ========
// amlp[2304][15360] @ w2b[3072][15360]^T + b2, gated residual -> f32 out.
// Grid 9*24=216, 512 thr, LDS = 3*(256*64 + 128*64)*2 = 144 KiB.
// Tile t lives in buf t%3. Group t: ph0-2 stage tile t+2 into buf (t+2)%3
// (freed at end of group t-1); ph3 vmcnt(6) completes tile t+1 (its newest
// load was issued 5 phases earlier). Tail: skip stages, vmcnt(0).
__global__ __launch_bounds__(512, 2) void k_gemm2(const unsigned short* __restrict__ amlp,
    const unsigned short* __restrict__ w2b, const float* __restrict__ b2,
    const float* __restrict__ img, const float* __restrict__ txt,
    const float* __restrict__ gate, float* __restrict__ out) {
  __shared__ unsigned short As[3][256 * 64];
  __shared__ unsigned short Bs[3][128 * 64];
  const int K = N2CAT;        // 15360
  const int NT = K / 64;      // 240 K-tiles
  int tid = threadIdx.x, lane = tid & 63, wid = tid >> 6;
  int wr = wid >> 1, wc = wid & 1;

  int b = blockIdx.x;                       // 216 % 8 == 0
  int bsw = (b & 7) * 27 + (b >> 3);
  int bm = bsw % 9, bn = bsw / 9;

  const unsigned short* Ag = amlp + (size_t)bm * 256 * K;
  const unsigned short* Bg = w2b + (size_t)bn * 128 * K;

  int sgran = (lane & 7) ^ ((lane >> 3) & 7);
  int srow = wid * 16 + (lane >> 3);

#define STAGE2_A(bufi, t, hh) do { \
    gload16(Ag + (size_t)((hh)*128 + srow) * K + (t)*64 + sgran*8, \
            &As[bufi][((hh)*128 + wid*16) * 64]); \
    gload16(Ag + (size_t)((hh)*128 + 8 + srow) * K + (t)*64 + sgran*8, \
            &As[bufi][((hh)*128 + wid*16 + 8) * 64]); \
  } while (0)
#define STAGE2_B(bufi, t) do { \
    gload16(Bg + (size_t)(srow) * K + (t)*64 + sgran*8, \
            &Bs[bufi][(wid*16) * 64]); \
    gload16(Bg + (size_t)(8 + srow) * K + (t)*64 + sgran*8, \
            &Bs[bufi][(wid*16 + 8) * 64]); \
  } while (0)

  int rA = wr * 64 + (lane & 15);
  int rB = wc * 64 + (lane & 15);
  int qq = lane >> 4, l7 = lane & 7;

  f4 acc[4][4];
#pragma unroll
  for (int m = 0; m < 4; ++m)
#pragma unroll
    for (int n = 0; n < 4; ++n) acc[m][n] = (f4){0.f, 0.f, 0.f, 0.f};
  bf8 aL[2][2], aH[2][2], bL[2][2], bH[2][2];

#define RD2(buf, r, s) (*(const bf8*)&buf[(r) * 64 + ((((s)*4 + qq) ^ l7) << 3)])

  // GROUP2: C = buf of tile t (compile-time), SB = (C+2)%3, ts = t+2, full = (ts < NT)
#define GROUP2(C, SB, t, full) do { \
    /* ph0: aL + bL reads; stage (ts).A0; quad(0,0) */ \
    _Pragma("unroll") for (int m = 0; m < 2; ++m) \
      _Pragma("unroll") for (int s = 0; s < 2; ++s) aL[m][s] = RD2(As[C], rA + m*16, s); \
    _Pragma("unroll") for (int n = 0; n < 2; ++n) \
      _Pragma("unroll") for (int s = 0; s < 2; ++s) bL[n][s] = RD2(Bs[C], rB + n*16, s); \
    if (full) STAGE2_A(SB, (t) + 2, 0); \
    LGKM0(); \
    __builtin_amdgcn_s_setprio(1); \
    _Pragma("unroll") for (int m = 0; m < 2; ++m) \
      _Pragma("unroll") for (int n = 0; n < 2; ++n) \
        _Pragma("unroll") for (int s = 0; s < 2; ++s) \
          acc[m][n] = mfma16(aL[m][s], bL[n][s], acc[m][n]); \
    __builtin_amdgcn_s_setprio(0); \
    BAR(); \
    /* ph1: bH reads; stage (ts).A1; quad(0,1) */ \
    _Pragma("unroll") for (int n = 0; n < 2; ++n) \
      _Pragma("unroll") for (int s = 0; s < 2; ++s) bH[n][s] = RD2(Bs[C], rB + (n+2)*16, s); \
    if (full) STAGE2_A(SB, (t) + 2, 1); \
    LGKM0(); \
    __builtin_amdgcn_s_setprio(1); \
    _Pragma("unroll") for (int m = 0; m < 2; ++m) \
      _Pragma("unroll") for (int n = 0; n < 2; ++n) \
        _Pragma("unroll") for (int s = 0; s < 2; ++s) \
          acc[m][n+2] = mfma16(aL[m][s], bH[n][s], acc[m][n+2]); \
    __builtin_amdgcn_s_setprio(0); \
    BAR(); \
    /* ph2: aH reads; stage (ts).B0; quad(1,1) */ \
    _Pragma("unroll") for (int m = 0; m < 2; ++m) \
      _Pragma("unroll") for (int s = 0; s < 2; ++s) aH[m][s] = RD2(As[C], rA + (m+2)*16, s); \
    if (full) STAGE2_B(SB, (t) + 2); \
    LGKM0(); \
    __builtin_amdgcn_s_setprio(1); \
    _Pragma("unroll") for (int m = 0; m < 2; ++m) \
      _Pragma("unroll") for (int n = 0; n < 2; ++n) \
        _Pragma("unroll") for (int s = 0; s < 2; ++s) \
          acc[m+2][n+2] = mfma16(aH[m][s], bH[n][s], acc[m+2][n+2]); \
    __builtin_amdgcn_s_setprio(0); \
    BAR(); \
    /* ph3: quad(1,0); vmcnt completes tile t+1 */ \
    __builtin_amdgcn_s_setprio(1); \
    _Pragma("unroll") for (int m = 0; m < 2; ++m) \
      _Pragma("unroll") for (int n = 0; n < 2; ++n) \
        _Pragma("unroll") for (int s = 0; s < 2; ++s) \
          acc[m+2][n] = mfma16(aH[m][s], bL[n][s], acc[m+2][n]); \
    __builtin_amdgcn_s_setprio(0); \
    if (full) { VMCNT6(); } else { VMCNT0(); } \
    BAR(); \
  } while (0)

  // prologue: tiles 0 -> buf0, 1 -> buf1 (6 stage ops = 12 loads); vmcnt(6) completes tile0
  STAGE2_A(0, 0, 0); STAGE2_A(0, 0, 1); STAGE2_B(0, 0);
  STAGE2_A(1, 1, 0); STAGE2_A(1, 1, 1); STAGE2_B(1, 1);
  VMCNT6();
  BAR();

  for (int i = 0; i < NT / 3; ++i) {
    int t = 3 * i;
    GROUP2(0, 2, t,     (t + 2) < NT);
    GROUP2(1, 0, t + 1, (t + 3) < NT);
    GROUP2(2, 1, t + 2, (t + 4) < NT);
  }
  VMCNT0();

  int r0 = bm * 256 + wr * 64 + ((lane >> 4) << 2);
  int c0 = bn * 128 + wc * 64 + (lane & 15);
#pragma unroll
  for (int m = 0; m < 4; ++m) {
#pragma unroll
    for (int n = 0; n < 4; ++n) {
      int col = c0 + n * 16;
      float bias = b2[col];
      float gt = gate[col];
#pragma unroll
      for (int j = 0; j < 4; ++j) {
        int row = r0 + m * 16 + j;
        float v = acc[m][n][j] + bias;
        float res = (row < LI) ? img[(size_t)row * HID + col]
                               : txt[(size_t)(row - LI) * HID + col];
        out[(size_t)row * HID + col] = res + gt * v;
      }
    }
  }
#undef STAGE2_A
#undef STAGE2_B
#undef RD2
#undef GROUP2
}

// ---------------- per-(token,head) RMSNorm + RoPE on q,k (in place, bf16) ----------------
__global__ void k_qknorm(unsigned short* __restrict__ qkv, const float* __restrict__ qw,
                         const float* __restrict__ kw, const float* __restrict__ fcos,
                         const float* __restrict__ fsin) {
  int gw = (blockIdx.x * 256 + threadIdx.x) >> 6;
  int lane = threadIdx.x & 63;
  int token = gw / NHEAD, head = gw - token * NHEAD;
  bool dorope = token < LI;
  float c = 1.f, sn = 0.f;
  if (dorope) { c = fcos[token * HD + 2 * lane]; sn = fsin[token * HD + 2 * lane]; }
#pragma unroll
  for (int qk = 0; qk < 2; ++qk) {
    unsigned short* p = qkv + (size_t)token * QKVW + qk * HID + head * HD;
    unsigned u = ((const unsigned*)p)[lane];
    float x0 = bf2f((unsigned short)(u & 0xffff));
    float x1 = bf2f((unsigned short)(u >> 16));
    float ss = x0 * x0 + x1 * x1;
#pragma unroll
    for (int m2 = 32; m2; m2 >>= 1) ss += __shfl_xor(ss, m2);
    float inv = rsqrtf(ss * (1.f / HD) + 1e-6f);
    const float* w = qk ? kw : qw;
    float y0 = x0 * inv * w[2 * lane];
    float y1 = x1 * inv * w[2 * lane + 1];
    if (dorope) { float r0 = y0 * c - y1 * sn; float r1 = y1 * c + y0 * sn; y0 = r0; y1 = r1; }
    ((unsigned*)p)[lane] = ((unsigned)f2bf(y0)) | (((unsigned)f2bf(y1)) << 16);
  }
}

// ---------------- transpose V: qkv v-slice [S][24*128] -> vt [24][128][S] ----------------
__global__ void k_vt(const unsigned short* __restrict__ qkv, unsigned short* __restrict__ vt) {
  int b = blockIdx.x;                 // 24*36*2
  int h = b / 72; int rem = b - h * 72; int tt = rem >> 1; int dd = rem & 1;
  int t0 = tt * 64, d0 = dd * 64;
  __shared__ unsigned short tile[64 * 65];
  int tid = threadIdx.x;
#pragma unroll
  for (int j = 0; j < 2; ++j) {
    int idx = j * 256 + tid;
    int row = idx >> 3, s = idx & 7;
    us8 vv = *(const us8*)(qkv + (size_t)(t0 + row) * QKVW + 2 * HID + h * HD + d0 + s * 8);
#pragma unroll
    for (int i = 0; i < 8; ++i) tile[row * 65 + s * 8 + i] = vv[i];
  }
  __syncthreads();
#pragma unroll
  for (int j = 0; j < 2; ++j) {
    int idx = j * 256 + tid;
    int dr = idx >> 3, sl = idx & 7;
    us8 o;
#pragma unroll
    for (int i = 0; i < 8; ++i) o[i] = tile[(sl * 8 + i) * 65 + dr];
    *(us8*)(vt + (size_t)(h * HD + d0 + dr) * SEQ + t0 + sl * 8) = o;
  }
}

// ---------------- flash attention: 64-row Q tile per block, 4 waves, online softmax ----------------
__global__ __launch_bounds__(256) void k_attn(const unsigned short* __restrict__ qkv,
                                              const unsigned short* __restrict__ vt,
                                              unsigned short* __restrict__ amlp) {
  int b = blockIdx.x;                           // 864 = 24 heads * 36 qtiles
  int bsw = (b & 7) * 108 + (b >> 3);
  int head = bsw / 36, qt = bsw - head * 36;
  int tid = threadIdx.x, lane = tid & 63, wv = tid >> 6;
  __shared__ unsigned short Qs[64 * 128], Ks[64 * 128], Vs[128 * 64], Ps[64 * 64];
  int qbase = qt * 64;

  { // stage Q once (swizzled source, linear LDS)
    int row = tid >> 4, sl = tid & 15;
    int slg = sl ^ (row & 7);
    const unsigned short* qg = qkv + (size_t)(qbase + row) * QKVW + head * HD + slg * 8;
#pragma unroll
    for (int j = 0; j < 4; ++j)
      gload16(qg + (size_t)(j * 16) * QKVW, &Qs[(j * 256 + tid) * 8]);
  }

  float mrun[4], lrun[4];
  f4 oacc[8];
#pragma unroll
  for (int j = 0; j < 4; ++j) { mrun[j] = -1e30f; lrun[j] = 0.f; }
#pragma unroll
  for (int n = 0; n < 8; ++n) oacc[n] = (f4){0.f, 0.f, 0.f, 0.f};
  bf8 qf[4];

  for (int kt = 0; kt < SEQ / 64; ++kt) {
    __syncthreads();
    { // stage K tile [64][128]
      int rloc = tid >> 4, sl = tid & 15, slg = sl ^ (rloc & 7);
      const unsigned short* kg =
          qkv + HID + (size_t)(kt * 64 + rloc) * QKVW + head * HD + slg * 8;
#pragma unroll
      for (int j = 0; j < 4; ++j) gload16(kg + (size_t)(j * 16) * QKVW, &Ks[(j * 256 + tid) * 8]);
    }
    { // stage V^T tile [128][64]
      int rloc = tid >> 3, sl = tid & 7, slg = sl ^ (rloc & 7);
      const unsigned short* vg = vt + (size_t)(head * HD + rloc) * SEQ + kt * 64 + slg * 8;
#pragma unroll
      for (int j = 0; j < 4; ++j) gload16(vg + (size_t)(j * 32) * SEQ, &Vs[(j * 256 + tid) * 8]);
    }
    __syncthreads();
    if (kt == 0) {
#pragma unroll
      for (int kk = 0; kk < 4; ++kk) {
        int row = wv * 16 + (lane & 15);
        int col = (kk * 32 + ((lane >> 4) * 8)) ^ ((lane & 7) << 3);
        qf[kk] = *(const bf8*)&Qs[row * 128 + col];
      }
    }
    // QK^T -> sacc[n] : S[16q][64k] per wave
    f4 sacc[4];
#pragma unroll
    for (int n = 0; n < 4; ++n) sacc[n] = (f4){0.f, 0.f, 0.f, 0.f};
#pragma unroll
    for (int kk = 0; kk < 4; ++kk) {
#pragma unroll
      for (int n = 0; n < 4; ++n) {
        int row = n * 16 + (lane & 15);
        int col = (kk * 32 + ((lane >> 4) * 8)) ^ ((lane & 7) << 3);
        bf8 kf = *(const bf8*)&Ks[row * 128 + col];
        sacc[n] = mfma16(qf[kk], kf, sacc[n]);
      }
    }
    const float SC = 0.08838834764831845f;
    float mj[4];
#pragma unroll
    for (int j = 0; j < 4; ++j)
      mj[j] = fmaxf(fmaxf(sacc[0][j], sacc[1][j]), fmaxf(sacc[2][j], sacc[3][j]));
#pragma unroll
    for (int j = 0; j < 4; ++j) {
#pragma unroll
      for (int mk = 8; mk; mk >>= 1) mj[j] = fmaxf(mj[j], __shfl_xor(mj[j], mk));
    }
    float resc[4], psum[4];
#pragma unroll
    for (int j = 0; j < 4; ++j) {
      float nm = fmaxf(mrun[j], mj[j] * SC);
      resc[j] = __expf(mrun[j] - nm);
      mrun[j] = nm;
      psum[j] = 0.f;
    }
#pragma unroll
    for (int n = 0; n < 4; ++n) {
#pragma unroll
      for (int j = 0; j < 4; ++j) {
        float p = __expf(sacc[n][j] * SC - mrun[j]);
        psum[j] += p;
        int row = wv * 16 + ((lane >> 4) << 2) + j;
        int col = (n * 16 + (lane & 15)) ^ ((row & 7) << 3);
        Ps[row * 64 + col] = f2bf(p);
      }
    }
#pragma unroll
    for (int j = 0; j < 4; ++j) {
#pragma unroll
      for (int mk = 8; mk; mk >>= 1) psum[j] += __shfl_xor(psum[j], mk);
      lrun[j] = lrun[j] * resc[j] + psum[j];
    }
#pragma unroll
    for (int n = 0; n < 8; ++n) {
#pragma unroll
      for (int j = 0; j < 4; ++j) oacc[n][j] *= resc[j];
    }
    // PV
#pragma unroll
    for (int kk = 0; kk < 2; ++kk) {
      int prow = wv * 16 + (lane & 15);
      int pcol = (kk * 32 + ((lane >> 4) * 8)) ^ ((lane & 7) << 3);
      bf8 pa = *(const bf8*)&Ps[prow * 64 + pcol];
#pragma unroll
      for (int n = 0; n < 8; ++n) {
        int vrow = n * 16 + (lane & 15);
        int vcol = (kk * 32 + ((lane >> 4) * 8)) ^ ((vrow & 7) << 3);
        bf8 vf = *(const bf8*)&Vs[vrow * 64 + vcol];
        oacc[n] = mfma16(pa, vf, oacc[n]);
      }
    }
  }
  // epilogue: O /= l, write bf16 into attnmlp cols [0,3072)
#pragma unroll
  for (int j = 0; j < 4; ++j) {
    float invl = 1.f / lrun[j];
    int row = qbase + wv * 16 + ((lane >> 4) << 2) + j;
#pragma unroll
    for (int n = 0; n < 8; ++n) {
      int col = head * HD + n * 16 + (lane & 15);
      amlp[(size_t)row * N2CAT + col] = f2bf(oacc[n][j] * invl);
    }
  }
}

extern "C" void kernel_launch(void* const* d_in, const int* in_sizes, int n_in,
                              void* d_out, int out_size, void* d_ws, size_t ws_size,
                              hipStream_t stream) {
  (void)in_sizes; (void)n_in; (void)out_size; (void)ws_size;
  const float* img  = (const float*)d_in[0];
  const float* txt  = (const float*)d_in[1];
  const float* vec  = (const float*)d_in[2];
  const float* fcos = (const float*)d_in[3];
  const float* fsin = (const float*)d_in[4];
  const float* w1   = (const float*)d_in[5];
  const float* b1   = (const float*)d_in[6];
  const float* w2   = (const float*)d_in[7];
  const float* b2   = (const float*)d_in[8];
  const float* qnw  = (const float*)d_in[9];
  const float* knw  = (const float*)d_in[10];
  const float* mw   = (const float*)d_in[11];
  const float* mb   = (const float*)d_in[12];
  float* out = (float*)d_out;

  char* ws = (char*)d_ws;
  float*          mod  = (float*)(ws);                          // 36,864 B
  unsigned short* xmod = (unsigned short*)(ws + 40960);         // 14,155,776 B
  unsigned short* w1b  = (unsigned short*)(ws + 14196736);      // 132,120,576 B
  unsigned short* qkv  = (unsigned short*)(ws + 146317312);     // 42,467,328 B
  unsigned short* amlp = (unsigned short*)(ws + 188784640);     // 70,778,880 B (end ~259.6MB)
  unsigned short* vtb  = xmod;   // x_mod dead after GEMM1
  unsigned short* w2b  = w1b;    // w1 bf16 dead after GEMM1

  k_mod<<<QKVW / 4, 256, 0, stream>>>(vec, mw, mb, mod);
  k_lnmod<<<SEQ, 256, 0, stream>>>(img, txt, mod, xmod);
  k_f2bf<<<2048, 256, 0, stream>>>(w1, w1b, N1 * HID / 4);
  k_gemm1<<<756, 512, 0, stream>>>(xmod, w1b, b1, qkv, amlp);
  k_qknorm<<<SEQ * NHEAD / 4, 256, 0, stream>>>(qkv, qnw, knw, fcos, fsin);
  k_vt<<<NHEAD * 36 * 2, 256, 0, stream>>>(qkv, vtb);
  k_f2bf<<<2048, 256, 0, stream>>>(w2, w2b, HID * N2CAT / 4);
  k_attn<<<864, 256, 0, stream>>>(qkv, vtb, amlp);
  k_gemm2<<<216, 512, 0, stream>>>(amlp, w2b, b2, img, txt, mod + 2 * HID, out);
}